// Round 13
// baseline (474.558 us; speedup 1.0000x reference)
//
#include <hip/hip_runtime.h>
#include <hip/hip_bf16.h>

typedef unsigned short u16;
typedef unsigned int u32;
typedef __attribute__((ext_vector_type(8))) short bf16x8;
typedef __attribute__((ext_vector_type(4))) float f32x4;
typedef __attribute__((ext_vector_type(4))) u32 u32x4;

#define BATCH 16384
#define NLEVS 60

#define SFC_OFF ((size_t)BATCH * NLEVS * 4)
#define MEM_OFF (SFC_OFF + (size_t)BATCH * 3)

// packed u16 plane offsets (in u16 units, from wpk) — layout validated r5-r12
#define W1IH_HI 0
#define W1IH_LO 8192
#define W1HH_HI 16384
#define W1HH_LO 32768
#define W2IH_HI 49152
#define W2IH_LO 65536
#define W2HH_HI 81920
#define W2HH_LO 98304
#define WHD_HI  114688
#define WHD_LO  116736

#define WPK_BYTE_OFF 4096
#define WS_R1_BYTE_OFF 262144

// gate prescale: i,f,o by -log2(e) (sigmoid), g by +2*log2(e) (tanh)
#define SIGK -1.4426950408889634f
#define TANK  2.8853900817779268f

#define MFMA(a, b, c) __builtin_amdgcn_mfma_f32_16x16x32_bf16((a), (b), (c), 0, 0, 0)

__device__ __forceinline__ float bf2f(u16 u) {
    union { u32 i; float f; } v; v.i = (u32)u << 16; return v.f;
}
__device__ __forceinline__ u16 f2bf(float f) {
    __hip_bfloat16 b = __float2bfloat16(f);
    u16 u; __builtin_memcpy(&u, &b, 2); return u;
}
__device__ __forceinline__ void split2(float w, u16& hi, u16& lo) {
    u16 h = f2bf(w);
    hi = h;
    lo = f2bf(w - bf2f(h));
}
__device__ __forceinline__ float tanh_(float x) {
    float ax = fabsf(x);
    float e  = __builtin_amdgcn_exp2f(-TANK * ax);
    float t  = (1.0f - e) * __builtin_amdgcn_rcpf(1.0f + e);
    return copysignf(t, x);
}

// Pack all weights to bf16 hi/lo planes with gate prescale; fuse biases and
// Wout@Wlat head (heads unscaled). Validated r5-r12.
__global__ void setup_pack(const float* __restrict__ W1ih, const float* __restrict__ W1hh,
                           const float* __restrict__ W2ih, const float* __restrict__ W2hh,
                           const float* __restrict__ Wlat, const float* __restrict__ Wout,
                           const float* __restrict__ Wsfco,
                           const float* __restrict__ b1ih, const float* __restrict__ b1hh,
                           const float* __restrict__ b2ih, const float* __restrict__ b2hh,
                           const float* __restrict__ blat, const float* __restrict__ bout,
                           const float* __restrict__ bsfco,
                           float* __restrict__ wsf, u16* __restrict__ wpk)
{
    int t = blockIdx.x * 256 + threadIdx.x;
    if (t < 256) {
        float sc = ((t >> 6) == 2) ? TANK : SIGK;
        wsf[t] = (b1ih[t] + b1hh[t]) * sc; return;
    }
    if (t < 512) {
        int j = t - 256;
        float sc = ((j >> 6) == 2) ? TANK : SIGK;
        wsf[256 + j] = (b2ih[j] + b2hh[j]) * sc; return;
    }
    if (t < 544) {
        int j = t - 512; float v;
        if (j < 16) v = blat[j];
        else if (j < 20) { v = bout[j - 16]; for (int m = 0; m < 16; ++m) v += Wout[(j - 16) * 16 + m] * blat[m]; }
        else if (j < 23) v = bsfco[j - 20];
        else v = 0.f;
        wsf[512 + j] = v; return;
    }
    int u = t - 544;
    float w; int hi_off, lo_off, idx, gate = -1;
    if (u < 8192) {
        int col = u >> 5, k = u & 31;
        w = (k < 20) ? W1ih[col * 20 + k] : 0.f;
        hi_off = W1IH_HI; lo_off = W1IH_LO; idx = u; gate = col >> 6;
    } else if (u < 24576) {
        idx = u - 8192; w = W1hh[idx]; hi_off = W1HH_HI; lo_off = W1HH_LO; gate = idx >> 12;
    } else if (u < 40960) {
        idx = u - 24576; w = W2ih[idx]; hi_off = W2IH_HI; lo_off = W2IH_LO; gate = idx >> 12;
    } else if (u < 57344) {
        idx = u - 40960; w = W2hh[idx]; hi_off = W2HH_HI; lo_off = W2HH_LO; gate = idx >> 12;
    } else if (u < 59392) {
        idx = u - 57344; int hc = idx >> 6, k = idx & 63;
        if (hc < 16) w = Wlat[hc * 64 + k];
        else if (hc < 20) { w = 0.f; for (int m = 0; m < 16; ++m) w += Wout[(hc - 16) * 16 + m] * Wlat[m * 64 + k]; }
        else if (hc < 23) w = Wsfco[(hc - 20) * 64 + k];
        else w = 0.f;
        hi_off = WHD_HI; lo_off = WHD_LO;
    } else return;
    if (gate >= 0) w *= (gate == 2) ? TANK : SIGK;
    u16 h_, l_; split2(w, h_, l_);
    wpk[hi_off + idx] = h_;
    wpk[lo_off + idx] = l_;
}

// Fused gate epilogue (prescaled pre-activations). Validated r8-r12.
__device__ __forceinline__ float gate_act(float si, float sf, float sg, float so, float& c) {
    float ei = __builtin_amdgcn_exp2f(si);
    float ef = __builtin_amdgcn_exp2f(sf);
    float eo = __builtin_amdgcn_exp2f(so);
    float eg = __builtin_amdgcn_exp2f(-fabsf(sg));
    float p2 = copysignf(1.f - eg, sg) * __builtin_amdgcn_rcpf((1.f + ei) * (1.f + eg));
    c = fmaf(__builtin_amdgcn_rcpf(1.f + ef), c, p2);
    float ec = __builtin_amdgcn_exp2f(-fabsf(TANK * c));
    return copysignf(1.f - ec, c) * __builtin_amdgcn_rcpf((1.f + eo) * (1.f + ec));
}

// ============ xcvt: pre-convert x to bf16 [row][lev][24] (k 20..23 = 0) ======
__global__ __launch_bounds__(256)
void xcvt_kern(const float* __restrict__ in_main, const float* __restrict__ in_mem,
               u16* __restrict__ xb, int b_off, int njobs)
{
    int t = blockIdx.x * 256 + threadIdx.x;
    if (t >= njobs) return;
    const int q = t % 3;
    const int rl = t / 3;
    const int lev = rl % NLEVS;
    const int row = rl / NLEVS;               // chunk-local
    const size_t mi = (size_t)(b_off + row) * NLEVS + lev;
    float v[8];
    if (q == 0) {
        float4 a = *(const float4*)(in_main + mi * 4);
        float4 b = *(const float4*)(in_mem + mi * 16);
        v[0]=a.x; v[1]=a.y; v[2]=a.z; v[3]=a.w; v[4]=b.x; v[5]=b.y; v[6]=b.z; v[7]=b.w;
    } else if (q == 1) {
        float4 a = *(const float4*)(in_mem + mi * 16 + 4);
        float4 b = *(const float4*)(in_mem + mi * 16 + 8);
        v[0]=a.x; v[1]=a.y; v[2]=a.z; v[3]=a.w; v[4]=b.x; v[5]=b.y; v[6]=b.z; v[7]=b.w;
    } else {
        float4 a = *(const float4*)(in_mem + mi * 16 + 12);
        v[0]=a.x; v[1]=a.y; v[2]=a.z; v[3]=a.w; v[4]=0; v[5]=0; v[6]=0; v[7]=0;
    }
    u32 d[4];
#pragma unroll
    for (int p = 0; p < 4; ++p)
        d[p] = ((u32)f2bf(v[p*2+1]) << 16) | f2bf(v[p*2]);
    *(u32x4*)(xb + ((size_t)row * NLEVS + lev) * 24 + q * 8) = *(const u32x4*)d;
}

// ============ Kernel 1: LSTM1 (reversed levels), 2 tiles/wave ============
__global__ __launch_bounds__(256, 2)
void lstm1_kern(const u16* __restrict__ xb, const float* __restrict__ in_aux,
                const float* __restrict__ Wsfc1, const float* __restrict__ bsfc1,
                const float* __restrict__ Wsfc2, const float* __restrict__ bsfc2,
                const float* __restrict__ wsf, const u16* __restrict__ wpk,
                u16* __restrict__ r1, int b_off, int ch_rows)
{
    __shared__ __align__(16) u16 hAh[2][16][72], hAl[2][16][72];
    __shared__ __align__(16) u16 hBh[2][16][72], hBl[2][16][72];
    const int tid = threadIdx.x;
    const int lane = tid & 63, wv = tid >> 6;
    const int q = lane >> 4, l15 = lane & 15;
    const int llocA = blockIdx.x * 32 + l15;
    const int llocB = llocA + 16;
    const int aRowA = b_off + llocA;
    const int aRowB = b_off + llocB;
    const int crowA = b_off + blockIdx.x * 32 + q * 4;
    const int crowB = crowA + 16;
    const int unit = wv * 16 + l15;

    bf16x8 Bih_h[4], Bih_l[4], Bhh_h[4][2], Bhh_l[4][2];
    float bias[4];
#pragma unroll
    for (int g = 0; g < 4; ++g) {
        const int col = g * 64 + unit;
        Bih_h[g] = *(const bf16x8*)(wpk + W1IH_HI + col * 32 + q * 8);
        Bih_l[g] = *(const bf16x8*)(wpk + W1IH_LO + col * 32 + q * 8);
#pragma unroll
        for (int kt = 0; kt < 2; ++kt) {
            Bhh_h[g][kt] = *(const bf16x8*)(wpk + W1HH_HI + col * 64 + kt * 32 + q * 8);
            Bhh_l[g][kt] = *(const bf16x8*)(wpk + W1HH_LO + col * 64 + kt * 32 + q * 8);
        }
        bias[g] = wsf[col];
    }

    bf16x8 hfhA[2], hflA[2], hfhB[2], hflB[2];
    float cstA[4], cstB[4];

    // ---- init h0/c0 for both tiles
    {
        const float aA0 = in_aux[(size_t)aRowA * 3], aA1 = in_aux[(size_t)aRowA * 3 + 1], aA2 = in_aux[(size_t)aRowA * 3 + 2];
        const float aB0 = in_aux[(size_t)aRowB * 3], aB1 = in_aux[(size_t)aRowB * 3 + 1], aB2 = in_aux[(size_t)aRowB * 3 + 2];
#pragma unroll
        for (int kt = 0; kt < 2; ++kt) {
            u32 dhA[4], dlA[4], dhB[4], dlB[4];
#pragma unroll
            for (int p = 0; p < 4; ++p) {
                int k0 = kt * 32 + q * 8 + p * 2;
                float w0 = Wsfc1[k0*3], w1 = Wsfc1[k0*3+1], w2 = Wsfc1[k0*3+2], bb = bsfc1[k0];
                float w3 = Wsfc1[k0*3+3], w4 = Wsfc1[k0*3+4], w5 = Wsfc1[k0*3+5], bc = bsfc1[k0+1];
                float ha = tanh_(fmaf(aA0, w0, fmaf(aA1, w1, fmaf(aA2, w2, bb))));
                float hb = tanh_(fmaf(aA0, w3, fmaf(aA1, w4, fmaf(aA2, w5, bc))));
                u16 h1, l1, h2, l2; split2(ha, h1, l1); split2(hb, h2, l2);
                dhA[p] = ((u32)h2 << 16) | h1; dlA[p] = ((u32)l2 << 16) | l1;
                ha = tanh_(fmaf(aB0, w0, fmaf(aB1, w1, fmaf(aB2, w2, bb))));
                hb = tanh_(fmaf(aB0, w3, fmaf(aB1, w4, fmaf(aB2, w5, bc))));
                split2(ha, h1, l1); split2(hb, h2, l2);
                dhB[p] = ((u32)h2 << 16) | h1; dlB[p] = ((u32)l2 << 16) | l1;
            }
            __builtin_memcpy(&hfhA[kt], dhA, 16); __builtin_memcpy(&hflA[kt], dlA, 16);
            __builtin_memcpy(&hfhB[kt], dhB, 16); __builtin_memcpy(&hflB[kt], dlB, 16);
        }
#pragma unroll
        for (int r = 0; r < 4; ++r) {
            float w0 = Wsfc2[unit*3], w1 = Wsfc2[unit*3+1], w2 = Wsfc2[unit*3+2], bb = bsfc2[unit];
            const size_t grA = (size_t)(crowA + r) * 3;
            cstA[r] = tanh_(fmaf(in_aux[grA], w0, fmaf(in_aux[grA+1], w1, fmaf(in_aux[grA+2], w2, bb))));
            const size_t grB = (size_t)(crowB + r) * 3;
            cstB[r] = tanh_(fmaf(in_aux[grB], w0, fmaf(in_aux[grB+1], w1, fmaf(in_aux[grB+2], w2, bb))));
        }
    }

    bf16x8 axA = {}, axB = {};
    if (q < 3) {
        axA = *(const bf16x8*)(xb + ((size_t)llocA * NLEVS + 59) * 24 + q * 8);
        axB = *(const bf16x8*)(xb + ((size_t)llocB * NLEVS + 59) * 24 + q * 8);
    }

#pragma unroll 1
    for (int t = 0; t < NLEVS; ++t) {
        const int lev = 59 - t;
        const int buf = t & 1;
        bf16x8 xA = axA, xB = axB;
        if (t < 59 && q < 3) {
            axA = *(const bf16x8*)(xb + ((size_t)llocA * NLEVS + (lev - 1)) * 24 + q * 8);
            axB = *(const bf16x8*)(xb + ((size_t)llocB * NLEVS + (lev - 1)) * 24 + q * 8);
        }
        f32x4 CA[4], CB[4];
#pragma unroll
        for (int g = 0; g < 4; ++g) {
            f32x4 a = {bias[g], bias[g], bias[g], bias[g]};
            a = MFMA(xA, Bih_h[g], a);
            a = MFMA(xA, Bih_l[g], a);
#pragma unroll
            for (int kt = 0; kt < 2; ++kt) {
                a = MFMA(hfhA[kt], Bhh_h[g][kt], a);
                a = MFMA(hflA[kt], Bhh_h[g][kt], a);
                a = MFMA(hfhA[kt], Bhh_l[g][kt], a);
            }
            CA[g] = a;
            f32x4 b = {bias[g], bias[g], bias[g], bias[g]};
            b = MFMA(xB, Bih_h[g], b);
            b = MFMA(xB, Bih_l[g], b);
#pragma unroll
            for (int kt = 0; kt < 2; ++kt) {
                b = MFMA(hfhB[kt], Bhh_h[g][kt], b);
                b = MFMA(hflB[kt], Bhh_h[g][kt], b);
                b = MFMA(hfhB[kt], Bhh_l[g][kt], b);
            }
            CB[g] = b;
        }
#pragma unroll
        for (int r = 0; r < 4; ++r) {
            float h = gate_act(CA[0][r], CA[1][r], CA[2][r], CA[3][r], cstA[r]);
            u16 hh_, hl_; split2(h, hh_, hl_);
            hAh[buf][q * 4 + r][unit] = hh_;
            hAl[buf][q * 4 + r][unit] = hl_;
            h = gate_act(CB[0][r], CB[1][r], CB[2][r], CB[3][r], cstB[r]);
            split2(h, hh_, hl_);
            hBh[buf][q * 4 + r][unit] = hh_;
            hBl[buf][q * 4 + r][unit] = hl_;
        }
        __syncthreads();
#pragma unroll
        for (int kt = 0; kt < 2; ++kt) {
            hfhA[kt] = *(const bf16x8*)&hAh[buf][l15][kt * 32 + q * 8];
            hflA[kt] = *(const bf16x8*)&hAl[buf][l15][kt * 32 + q * 8];
            hfhB[kt] = *(const bf16x8*)&hBh[buf][l15][kt * 32 + q * 8];
            hflB[kt] = *(const bf16x8*)&hBl[buf][l15][kt * 32 + q * 8];
            u32x4 svA; __builtin_memcpy(&svA, &hfhA[kt], 16);
            u32x4 svB; __builtin_memcpy(&svB, &hfhB[kt], 16);
            *(u32x4*)(r1 + ((size_t)(lev * 8 + kt * 4 + q) * ch_rows + llocA) * 8) = svA;
            *(u32x4*)(r1 + ((size_t)(lev * 8 + kt * 4 + q) * ch_rows + llocB) * 8) = svB;
        }
    }
}

// ============ Kernel 2: LSTM2 forward + fused heads, 2 tiles/wave ============
__global__ __launch_bounds__(256, 2)
void lstm2_kern(const float* __restrict__ in_aux,
                const float* __restrict__ Wtoa1, const float* __restrict__ btoa1,
                const float* __restrict__ Wtoa2, const float* __restrict__ btoa2,
                const float* __restrict__ wsf, const u16* __restrict__ wpk,
                const u16* __restrict__ r1, int b_off, int ch_rows,
                float* __restrict__ out)
{
    __shared__ __align__(16) u16 hAh[2][16][72], hAl[2][16][72];
    __shared__ __align__(16) u16 hBh[2][16][72], hBl[2][16][72];
    const int tid = threadIdx.x;
    const int lane = tid & 63, wv = tid >> 6;
    const int q = lane >> 4, l15 = lane & 15;
    const int llocA = blockIdx.x * 32 + l15;
    const int llocB = llocA + 16;
    const int aRowA = b_off + llocA;
    const int aRowB = b_off + llocB;
    const int crowA = b_off + blockIdx.x * 32 + q * 4;
    const int crowB = crowA + 16;
    const int unit = wv * 16 + l15;

    bf16x8 Bih_h[4][2], Bih_l[4][2], Bhh_h[4][2], Bhh_l[4][2];
    float bias[4];
#pragma unroll
    for (int g = 0; g < 4; ++g) {
        const int col = g * 64 + unit;
#pragma unroll
        for (int kt = 0; kt < 2; ++kt) {
            Bih_h[g][kt] = *(const bf16x8*)(wpk + W2IH_HI + col * 64 + kt * 32 + q * 8);
            Bih_l[g][kt] = *(const bf16x8*)(wpk + W2IH_LO + col * 64 + kt * 32 + q * 8);
            Bhh_h[g][kt] = *(const bf16x8*)(wpk + W2HH_HI + col * 64 + kt * 32 + q * 8);
            Bhh_l[g][kt] = *(const bf16x8*)(wpk + W2HH_LO + col * 64 + kt * 32 + q * 8);
        }
        bias[g] = wsf[256 + col];
    }
    // head frags on waves 0/1 (tile wv of head cols); serve both row-tiles
    bf16x8 Bhd_h[2], Bhd_l[2];
    float bhd = 0.f;
    if (wv < 2) {
        const int hc = wv * 16 + l15;
#pragma unroll
        for (int kt = 0; kt < 2; ++kt) {
            Bhd_h[kt] = *(const bf16x8*)(wpk + WHD_HI + hc * 64 + kt * 32 + q * 8);
            Bhd_l[kt] = *(const bf16x8*)(wpk + WHD_LO + hc * 64 + kt * 32 + q * 8);
        }
        bhd = wsf[512 + hc];
    }

    bf16x8 hfhA[2], hflA[2], hfhB[2], hflB[2];
    float cstA[4], cstB[4];
    {
        const float toaA = in_aux[(size_t)aRowA * 3 + 1];
        const float toaB = in_aux[(size_t)aRowB * 3 + 1];
#pragma unroll
        for (int kt = 0; kt < 2; ++kt) {
            u32 dhA[4], dlA[4], dhB[4], dlB[4];
#pragma unroll
            for (int p = 0; p < 4; ++p) {
                int k0 = kt * 32 + q * 8 + p * 2;
                float w0 = Wtoa2[k0], b0 = btoa2[k0], w1 = Wtoa2[k0 + 1], b1 = btoa2[k0 + 1];
                float ha = fmaf(toaA, w0, b0), hb = fmaf(toaA, w1, b1);
                u16 h1, l1, h2, l2; split2(ha, h1, l1); split2(hb, h2, l2);
                dhA[p] = ((u32)h2 << 16) | h1; dlA[p] = ((u32)l2 << 16) | l1;
                ha = fmaf(toaB, w0, b0); hb = fmaf(toaB, w1, b1);
                split2(ha, h1, l1); split2(hb, h2, l2);
                dhB[p] = ((u32)h2 << 16) | h1; dlB[p] = ((u32)l2 << 16) | l1;
            }
            __builtin_memcpy(&hfhA[kt], dhA, 16); __builtin_memcpy(&hflA[kt], dlA, 16);
            __builtin_memcpy(&hfhB[kt], dhB, 16); __builtin_memcpy(&hflB[kt], dlB, 16);
        }
#pragma unroll
        for (int r = 0; r < 4; ++r) {
            cstA[r] = fmaf(in_aux[(size_t)(crowA + r) * 3 + 1], Wtoa1[unit], btoa1[unit]);
            cstB[r] = fmaf(in_aux[(size_t)(crowB + r) * 3 + 1], Wtoa1[unit], btoa1[unit]);
        }
    }

    bf16x8 pxA[2], pxB[2];
#pragma unroll
    for (int kt = 0; kt < 2; ++kt) {
        pxA[kt] = *(const bf16x8*)(r1 + ((size_t)(kt * 4 + q) * ch_rows + llocA) * 8);
        pxB[kt] = *(const bf16x8*)(r1 + ((size_t)(kt * 4 + q) * ch_rows + llocB) * 8);
    }

#pragma unroll 1
    for (int lev = 0; lev < NLEVS; ++lev) {
        const int buf = lev & 1;
        bf16x8 axA[2], axB[2];
        axA[0] = pxA[0]; axA[1] = pxA[1];
        axB[0] = pxB[0]; axB[1] = pxB[1];
        if (lev < 59) {
#pragma unroll
            for (int kt = 0; kt < 2; ++kt) {
                pxA[kt] = *(const bf16x8*)(r1 + ((size_t)((lev + 1) * 8 + kt * 4 + q) * ch_rows + llocA) * 8);
                pxB[kt] = *(const bf16x8*)(r1 + ((size_t)((lev + 1) * 8 + kt * 4 + q) * ch_rows + llocB) * 8);
            }
        }
        f32x4 CA[4], CB[4];
#pragma unroll
        for (int g = 0; g < 4; ++g) {
            f32x4 a = {bias[g], bias[g], bias[g], bias[g]};
#pragma unroll
            for (int kt = 0; kt < 2; ++kt) {
                a = MFMA(axA[kt], Bih_h[g][kt], a);
                a = MFMA(axA[kt], Bih_l[g][kt], a);
                a = MFMA(hfhA[kt], Bhh_h[g][kt], a);
                a = MFMA(hflA[kt], Bhh_h[g][kt], a);
                a = MFMA(hfhA[kt], Bhh_l[g][kt], a);
            }
            CA[g] = a;
            f32x4 b = {bias[g], bias[g], bias[g], bias[g]};
#pragma unroll
            for (int kt = 0; kt < 2; ++kt) {
                b = MFMA(axB[kt], Bih_h[g][kt], b);
                b = MFMA(axB[kt], Bih_l[g][kt], b);
                b = MFMA(hfhB[kt], Bhh_h[g][kt], b);
                b = MFMA(hflB[kt], Bhh_h[g][kt], b);
                b = MFMA(hfhB[kt], Bhh_l[g][kt], b);
            }
            CB[g] = b;
        }
#pragma unroll
        for (int r = 0; r < 4; ++r) {
            float h = gate_act(CA[0][r], CA[1][r], CA[2][r], CA[3][r], cstA[r]);
            u16 hh_, hl_; split2(h, hh_, hl_);
            hAh[buf][q * 4 + r][unit] = hh_;
            hAl[buf][q * 4 + r][unit] = hl_;
            h = gate_act(CB[0][r], CB[1][r], CB[2][r], CB[3][r], cstB[r]);
            split2(h, hh_, hl_);
            hBh[buf][q * 4 + r][unit] = hh_;
            hBl[buf][q * 4 + r][unit] = hl_;
        }
        __syncthreads();
#pragma unroll
        for (int kt = 0; kt < 2; ++kt) {
            hfhA[kt] = *(const bf16x8*)&hAh[buf][l15][kt * 32 + q * 8];
            hflA[kt] = *(const bf16x8*)&hAl[buf][l15][kt * 32 + q * 8];
            hfhB[kt] = *(const bf16x8*)&hBh[buf][l15][kt * 32 + q * 8];
            hflB[kt] = *(const bf16x8*)&hBl[buf][l15][kt * 32 + q * 8];
        }
        // fused heads (waves 0/1), both tiles; numerics identical to r12
        if (wv < 2) {
            f32x4 a = {bhd, bhd, bhd, bhd};
            f32x4 b = {bhd, bhd, bhd, bhd};
#pragma unroll
            for (int kt = 0; kt < 2; ++kt) {
                a = MFMA(hfhA[kt], Bhd_h[kt], a);
                a = MFMA(hfhA[kt], Bhd_l[kt], a);
                b = MFMA(hfhB[kt], Bhd_h[kt], b);
                b = MFMA(hfhB[kt], Bhd_l[kt], b);
            }
#pragma unroll
            for (int r = 0; r < 4; ++r) {
                const size_t gbA = (size_t)(crowA + r);
                const size_t gbB = (size_t)(crowB + r);
                if (wv == 0) {
                    out[MEM_OFF + (gbA * NLEVS + lev) * 16 + l15] = tanh_(a[r]);
                    out[MEM_OFF + (gbB * NLEVS + lev) * 16 + l15] = tanh_(b[r]);
                } else {
                    if (l15 < 4) {
                        out[(gbA * NLEVS + lev) * 4 + l15] = a[r];
                        out[(gbB * NLEVS + lev) * 4 + l15] = b[r];
                    } else if (l15 < 7 && lev == NLEVS - 1) {
                        out[SFC_OFF + gbA * 3 + (l15 - 4)] = a[r];
                        out[SFC_OFF + gbB * 3 + (l15 - 4)] = b[r];
                    }
                }
            }
        }
    }
}

extern "C" void kernel_launch(void* const* d_in, const int* in_sizes, int n_in,
                              void* d_out, int out_size, void* d_ws, size_t ws_size,
                              hipStream_t stream) {
    const float* in_main = (const float*)d_in[0];
    const float* in_aux  = (const float*)d_in[1];
    const float* in_mem  = (const float*)d_in[2];
    const float* Wsfc1   = (const float*)d_in[3];
    const float* bsfc1   = (const float*)d_in[4];
    const float* Wsfc2   = (const float*)d_in[5];
    const float* bsfc2   = (const float*)d_in[6];
    const float* Wtoa1   = (const float*)d_in[7];
    const float* btoa1   = (const float*)d_in[8];
    const float* Wtoa2   = (const float*)d_in[9];
    const float* btoa2   = (const float*)d_in[10];
    const float* W1ih    = (const float*)d_in[11];
    const float* W1hh    = (const float*)d_in[12];
    const float* b1ih    = (const float*)d_in[13];
    const float* b1hh    = (const float*)d_in[14];
    const float* W2ih    = (const float*)d_in[15];
    const float* W2hh    = (const float*)d_in[16];
    const float* b2ih    = (const float*)d_in[17];
    const float* b2hh    = (const float*)d_in[18];
    const float* Wlat    = (const float*)d_in[19];
    const float* blat    = (const float*)d_in[20];
    const float* Wout    = (const float*)d_in[21];
    const float* bout    = (const float*)d_in[22];
    const float* Wsfco   = (const float*)d_in[23];
    const float* bsfco   = (const float*)d_in[24];
    float* out           = (float*)d_out;

    float* wsf    = (float*)d_ws;
    u16*   wpk    = (u16*)((char*)d_ws + WPK_BYTE_OFF);
    u16*   rbase  = (u16*)((char*)d_ws + WS_R1_BYTE_OFF);

    setup_pack<<<235, 256, 0, stream>>>(W1ih, W1hh, W2ih, W2hh, Wlat, Wout, Wsfco,
                                        b1ih, b1hh, b2ih, b2hh, blat, bout, bsfco,
                                        wsf, wpk);

    const size_t avail = (ws_size > WS_R1_BYTE_OFF) ? ws_size - WS_R1_BYTE_OFF : 0;
    // per row: xb = 60*24*2 = 2880 B, r1 = 60*64*2 = 7680 B
    const size_t per_row = 2880 + 7680;
    size_t rows = avail / per_row;
    rows &= ~(size_t)31;
    if (rows > BATCH) rows = BATCH;
    if (rows < 32) rows = 32;

    for (int off = 0; off < BATCH; off += (int)rows) {
        int nr = (BATCH - off < (int)rows) ? (BATCH - off) : (int)rows;
        u16* xb = rbase;
        u16* r1 = rbase + (size_t)nr * NLEVS * 24;
        const int njobs = nr * NLEVS * 3;
        xcvt_kern<<<(njobs + 255) / 256, 256, 0, stream>>>(in_main, in_mem, xb, off, njobs);
        lstm1_kern<<<nr / 32, 256, 0, stream>>>(
            xb, in_aux, Wsfc1, bsfc1, Wsfc2, bsfc2, wsf, wpk, r1, off, nr);
        lstm2_kern<<<nr / 32, 256, 0, stream>>>(
            in_aux, Wtoa1, btoa1, Wtoa2, btoa2, wsf, wpk, r1, off, nr, out);
    }
}

// Round 14
// 352.779 us; speedup vs baseline: 1.3452x; 1.3452x over previous
//
#include <hip/hip_runtime.h>
#include <hip/hip_bf16.h>

typedef unsigned short u16;
typedef unsigned int u32;
typedef __attribute__((ext_vector_type(8))) short bf16x8;
typedef __attribute__((ext_vector_type(4))) float f32x4;
typedef __attribute__((ext_vector_type(4))) u32 u32x4;

#define BATCH 16384
#define NLEVS 60

#define SFC_OFF ((size_t)BATCH * NLEVS * 4)
#define MEM_OFF (SFC_OFF + (size_t)BATCH * 3)

// packed u16 plane offsets (in u16 units, from wpk) — layout validated r5-r13
#define W1IH_HI 0
#define W1IH_LO 8192
#define W1HH_HI 16384
#define W1HH_LO 32768
#define W2IH_HI 49152
#define W2IH_LO 65536
#define W2HH_HI 81920
#define W2HH_LO 98304
#define WHD_HI  114688
#define WHD_LO  116736

#define WPK_BYTE_OFF 4096
#define WS_R1_BYTE_OFF 262144

// gate prescale: i,f,o by -log2(e) (sigmoid), g by +2*log2(e) (tanh)
#define SIGK -1.4426950408889634f
#define TANK  2.8853900817779268f

#define MFMA(a, b, c) __builtin_amdgcn_mfma_f32_16x16x32_bf16((a), (b), (c), 0, 0, 0)

__device__ __forceinline__ float bf2f(u16 u) {
    union { u32 i; float f; } v; v.i = (u32)u << 16; return v.f;
}
__device__ __forceinline__ u16 f2bf(float f) {
    __hip_bfloat16 b = __float2bfloat16(f);
    u16 u; __builtin_memcpy(&u, &b, 2); return u;
}
__device__ __forceinline__ void split2(float w, u16& hi, u16& lo) {
    u16 h = f2bf(w);
    hi = h;
    lo = f2bf(w - bf2f(h));
}
__device__ __forceinline__ float tanh_(float x) {
    float ax = fabsf(x);
    float e  = __builtin_amdgcn_exp2f(-TANK * ax);
    float t  = (1.0f - e) * __builtin_amdgcn_rcpf(1.0f + e);
    return copysignf(t, x);
}

// Pack all weights to bf16 hi/lo planes with gate prescale; fuse biases and
// Wout@Wlat head (heads unscaled). Validated r5-r13.
__global__ void setup_pack(const float* __restrict__ W1ih, const float* __restrict__ W1hh,
                           const float* __restrict__ W2ih, const float* __restrict__ W2hh,
                           const float* __restrict__ Wlat, const float* __restrict__ Wout,
                           const float* __restrict__ Wsfco,
                           const float* __restrict__ b1ih, const float* __restrict__ b1hh,
                           const float* __restrict__ b2ih, const float* __restrict__ b2hh,
                           const float* __restrict__ blat, const float* __restrict__ bout,
                           const float* __restrict__ bsfco,
                           float* __restrict__ wsf, u16* __restrict__ wpk)
{
    int t = blockIdx.x * 256 + threadIdx.x;
    if (t < 256) {
        float sc = ((t >> 6) == 2) ? TANK : SIGK;
        wsf[t] = (b1ih[t] + b1hh[t]) * sc; return;
    }
    if (t < 512) {
        int j = t - 256;
        float sc = ((j >> 6) == 2) ? TANK : SIGK;
        wsf[256 + j] = (b2ih[j] + b2hh[j]) * sc; return;
    }
    if (t < 544) {
        int j = t - 512; float v;
        if (j < 16) v = blat[j];
        else if (j < 20) { v = bout[j - 16]; for (int m = 0; m < 16; ++m) v += Wout[(j - 16) * 16 + m] * blat[m]; }
        else if (j < 23) v = bsfco[j - 20];
        else v = 0.f;
        wsf[512 + j] = v; return;
    }
    int u = t - 544;
    float w; int hi_off, lo_off, idx, gate = -1;
    if (u < 8192) {
        int col = u >> 5, k = u & 31;
        w = (k < 20) ? W1ih[col * 20 + k] : 0.f;
        hi_off = W1IH_HI; lo_off = W1IH_LO; idx = u; gate = col >> 6;
    } else if (u < 24576) {
        idx = u - 8192; w = W1hh[idx]; hi_off = W1HH_HI; lo_off = W1HH_LO; gate = idx >> 12;
    } else if (u < 40960) {
        idx = u - 24576; w = W2ih[idx]; hi_off = W2IH_HI; lo_off = W2IH_LO; gate = idx >> 12;
    } else if (u < 57344) {
        idx = u - 40960; w = W2hh[idx]; hi_off = W2HH_HI; lo_off = W2HH_LO; gate = idx >> 12;
    } else if (u < 59392) {
        idx = u - 57344; int hc = idx >> 6, k = idx & 63;
        if (hc < 16) w = Wlat[hc * 64 + k];
        else if (hc < 20) { w = 0.f; for (int m = 0; m < 16; ++m) w += Wout[(hc - 16) * 16 + m] * Wlat[m * 64 + k]; }
        else if (hc < 23) w = Wsfco[(hc - 20) * 64 + k];
        else w = 0.f;
        hi_off = WHD_HI; lo_off = WHD_LO;
    } else return;
    if (gate >= 0) w *= (gate == 2) ? TANK : SIGK;
    u16 h_, l_; split2(w, h_, l_);
    wpk[hi_off + idx] = h_;
    wpk[lo_off + idx] = l_;
}

// Fused gate epilogue (prescaled pre-activations). Validated r8-r13.
__device__ __forceinline__ float gate_act(float si, float sf, float sg, float so, float& c) {
    float ei = __builtin_amdgcn_exp2f(si);
    float ef = __builtin_amdgcn_exp2f(sf);
    float eo = __builtin_amdgcn_exp2f(so);
    float eg = __builtin_amdgcn_exp2f(-fabsf(sg));
    float p2 = copysignf(1.f - eg, sg) * __builtin_amdgcn_rcpf((1.f + ei) * (1.f + eg));
    c = fmaf(__builtin_amdgcn_rcpf(1.f + ef), c, p2);
    float ec = __builtin_amdgcn_exp2f(-fabsf(TANK * c));
    return copysignf(1.f - ec, c) * __builtin_amdgcn_rcpf((1.f + eo) * (1.f + ec));
}

// ============ xcvt: pre-convert x to bf16 [row][lev][24] (k 20..23 = 0) ======
__global__ __launch_bounds__(256)
void xcvt_kern(const float* __restrict__ in_main, const float* __restrict__ in_mem,
               u16* __restrict__ xb, int b_off, int njobs)
{
    int t = blockIdx.x * 256 + threadIdx.x;
    if (t >= njobs) return;
    const int q = t % 3;
    const int rl = t / 3;
    const int lev = rl % NLEVS;
    const int row = rl / NLEVS;               // chunk-local
    const size_t mi = (size_t)(b_off + row) * NLEVS + lev;
    float v[8];
    if (q == 0) {
        float4 a = *(const float4*)(in_main + mi * 4);
        float4 b = *(const float4*)(in_mem + mi * 16);
        v[0]=a.x; v[1]=a.y; v[2]=a.z; v[3]=a.w; v[4]=b.x; v[5]=b.y; v[6]=b.z; v[7]=b.w;
    } else if (q == 1) {
        float4 a = *(const float4*)(in_mem + mi * 16 + 4);
        float4 b = *(const float4*)(in_mem + mi * 16 + 8);
        v[0]=a.x; v[1]=a.y; v[2]=a.z; v[3]=a.w; v[4]=b.x; v[5]=b.y; v[6]=b.z; v[7]=b.w;
    } else {
        float4 a = *(const float4*)(in_mem + mi * 16 + 12);
        v[0]=a.x; v[1]=a.y; v[2]=a.z; v[3]=a.w; v[4]=0; v[5]=0; v[6]=0; v[7]=0;
    }
    u32 d[4];
#pragma unroll
    for (int p = 0; p < 4; ++p)
        d[p] = ((u32)f2bf(v[p*2+1]) << 16) | f2bf(v[p*2]);
    *(u32x4*)(xb + ((size_t)row * NLEVS + lev) * 24 + q * 8) = *(const u32x4*)d;
}

// ============ Kernel 1: LSTM1 (reversed levels), 2 tiles/wave (r12, 150us) ===
__global__ __launch_bounds__(256, 2)
void lstm1_kern(const u16* __restrict__ xb, const float* __restrict__ in_aux,
                const float* __restrict__ Wsfc1, const float* __restrict__ bsfc1,
                const float* __restrict__ Wsfc2, const float* __restrict__ bsfc2,
                const float* __restrict__ wsf, const u16* __restrict__ wpk,
                u16* __restrict__ r1, int b_off, int ch_rows)
{
    __shared__ __align__(16) u16 hAh[2][16][72], hAl[2][16][72];
    __shared__ __align__(16) u16 hBh[2][16][72], hBl[2][16][72];
    const int tid = threadIdx.x;
    const int lane = tid & 63, wv = tid >> 6;
    const int q = lane >> 4, l15 = lane & 15;
    const int llocA = blockIdx.x * 32 + l15;
    const int llocB = llocA + 16;
    const int aRowA = b_off + llocA;
    const int aRowB = b_off + llocB;
    const int crowA = b_off + blockIdx.x * 32 + q * 4;
    const int crowB = crowA + 16;
    const int unit = wv * 16 + l15;

    bf16x8 Bih_h[4], Bih_l[4], Bhh_h[4][2], Bhh_l[4][2];
    float bias[4];
#pragma unroll
    for (int g = 0; g < 4; ++g) {
        const int col = g * 64 + unit;
        Bih_h[g] = *(const bf16x8*)(wpk + W1IH_HI + col * 32 + q * 8);
        Bih_l[g] = *(const bf16x8*)(wpk + W1IH_LO + col * 32 + q * 8);
#pragma unroll
        for (int kt = 0; kt < 2; ++kt) {
            Bhh_h[g][kt] = *(const bf16x8*)(wpk + W1HH_HI + col * 64 + kt * 32 + q * 8);
            Bhh_l[g][kt] = *(const bf16x8*)(wpk + W1HH_LO + col * 64 + kt * 32 + q * 8);
        }
        bias[g] = wsf[col];
    }

    bf16x8 hfhA[2], hflA[2], hfhB[2], hflB[2];
    float cstA[4], cstB[4];

    {
        const float aA0 = in_aux[(size_t)aRowA * 3], aA1 = in_aux[(size_t)aRowA * 3 + 1], aA2 = in_aux[(size_t)aRowA * 3 + 2];
        const float aB0 = in_aux[(size_t)aRowB * 3], aB1 = in_aux[(size_t)aRowB * 3 + 1], aB2 = in_aux[(size_t)aRowB * 3 + 2];
#pragma unroll
        for (int kt = 0; kt < 2; ++kt) {
            u32 dhA[4], dlA[4], dhB[4], dlB[4];
#pragma unroll
            for (int p = 0; p < 4; ++p) {
                int k0 = kt * 32 + q * 8 + p * 2;
                float w0 = Wsfc1[k0*3], w1 = Wsfc1[k0*3+1], w2 = Wsfc1[k0*3+2], bb = bsfc1[k0];
                float w3 = Wsfc1[k0*3+3], w4 = Wsfc1[k0*3+4], w5 = Wsfc1[k0*3+5], bc = bsfc1[k0+1];
                float ha = tanh_(fmaf(aA0, w0, fmaf(aA1, w1, fmaf(aA2, w2, bb))));
                float hb = tanh_(fmaf(aA0, w3, fmaf(aA1, w4, fmaf(aA2, w5, bc))));
                u16 h1, l1, h2, l2; split2(ha, h1, l1); split2(hb, h2, l2);
                dhA[p] = ((u32)h2 << 16) | h1; dlA[p] = ((u32)l2 << 16) | l1;
                ha = tanh_(fmaf(aB0, w0, fmaf(aB1, w1, fmaf(aB2, w2, bb))));
                hb = tanh_(fmaf(aB0, w3, fmaf(aB1, w4, fmaf(aB2, w5, bc))));
                split2(ha, h1, l1); split2(hb, h2, l2);
                dhB[p] = ((u32)h2 << 16) | h1; dlB[p] = ((u32)l2 << 16) | l1;
            }
            __builtin_memcpy(&hfhA[kt], dhA, 16); __builtin_memcpy(&hflA[kt], dlA, 16);
            __builtin_memcpy(&hfhB[kt], dhB, 16); __builtin_memcpy(&hflB[kt], dlB, 16);
        }
#pragma unroll
        for (int r = 0; r < 4; ++r) {
            float w0 = Wsfc2[unit*3], w1 = Wsfc2[unit*3+1], w2 = Wsfc2[unit*3+2], bb = bsfc2[unit];
            const size_t grA = (size_t)(crowA + r) * 3;
            cstA[r] = tanh_(fmaf(in_aux[grA], w0, fmaf(in_aux[grA+1], w1, fmaf(in_aux[grA+2], w2, bb))));
            const size_t grB = (size_t)(crowB + r) * 3;
            cstB[r] = tanh_(fmaf(in_aux[grB], w0, fmaf(in_aux[grB+1], w1, fmaf(in_aux[grB+2], w2, bb))));
        }
    }

    bf16x8 axA = {}, axB = {};
    if (q < 3) {
        axA = *(const bf16x8*)(xb + ((size_t)llocA * NLEVS + 59) * 24 + q * 8);
        axB = *(const bf16x8*)(xb + ((size_t)llocB * NLEVS + 59) * 24 + q * 8);
    }

#pragma unroll 1
    for (int t = 0; t < NLEVS; ++t) {
        const int lev = 59 - t;
        const int buf = t & 1;
        bf16x8 xA = axA, xB = axB;
        if (t < 59 && q < 3) {
            axA = *(const bf16x8*)(xb + ((size_t)llocA * NLEVS + (lev - 1)) * 24 + q * 8);
            axB = *(const bf16x8*)(xb + ((size_t)llocB * NLEVS + (lev - 1)) * 24 + q * 8);
        }
        f32x4 CA[4], CB[4];
#pragma unroll
        for (int g = 0; g < 4; ++g) {
            f32x4 a = {bias[g], bias[g], bias[g], bias[g]};
            a = MFMA(xA, Bih_h[g], a);
            a = MFMA(xA, Bih_l[g], a);
#pragma unroll
            for (int kt = 0; kt < 2; ++kt) {
                a = MFMA(hfhA[kt], Bhh_h[g][kt], a);
                a = MFMA(hflA[kt], Bhh_h[g][kt], a);
                a = MFMA(hfhA[kt], Bhh_l[g][kt], a);
            }
            CA[g] = a;
            f32x4 b = {bias[g], bias[g], bias[g], bias[g]};
            b = MFMA(xB, Bih_h[g], b);
            b = MFMA(xB, Bih_l[g], b);
#pragma unroll
            for (int kt = 0; kt < 2; ++kt) {
                b = MFMA(hfhB[kt], Bhh_h[g][kt], b);
                b = MFMA(hflB[kt], Bhh_h[g][kt], b);
                b = MFMA(hfhB[kt], Bhh_l[g][kt], b);
            }
            CB[g] = b;
        }
#pragma unroll
        for (int r = 0; r < 4; ++r) {
            float h = gate_act(CA[0][r], CA[1][r], CA[2][r], CA[3][r], cstA[r]);
            u16 hh_, hl_; split2(h, hh_, hl_);
            hAh[buf][q * 4 + r][unit] = hh_;
            hAl[buf][q * 4 + r][unit] = hl_;
            h = gate_act(CB[0][r], CB[1][r], CB[2][r], CB[3][r], cstB[r]);
            split2(h, hh_, hl_);
            hBh[buf][q * 4 + r][unit] = hh_;
            hBl[buf][q * 4 + r][unit] = hl_;
        }
        __syncthreads();
#pragma unroll
        for (int kt = 0; kt < 2; ++kt) {
            hfhA[kt] = *(const bf16x8*)&hAh[buf][l15][kt * 32 + q * 8];
            hflA[kt] = *(const bf16x8*)&hAl[buf][l15][kt * 32 + q * 8];
            hfhB[kt] = *(const bf16x8*)&hBh[buf][l15][kt * 32 + q * 8];
            hflB[kt] = *(const bf16x8*)&hBl[buf][l15][kt * 32 + q * 8];
            u32x4 svA; __builtin_memcpy(&svA, &hfhA[kt], 16);
            u32x4 svB; __builtin_memcpy(&svB, &hfhB[kt], 16);
            *(u32x4*)(r1 + ((size_t)(lev * 8 + kt * 4 + q) * ch_rows + llocA) * 8) = svA;
            *(u32x4*)(r1 + ((size_t)(lev * 8 + kt * 4 + q) * ch_rows + llocB) * 8) = svB;
        }
    }
}

// ============ Kernel 2: LSTM2 + fused heads, 2 tiles/wave, LDS lo-weights ====
// Bih_l (x-path lo) and head frags staged to LDS once (tile-shared reads);
// resident regs: Bih_h/Bhh_h/Bhh_l = 96. Numerics bit-identical to r12.
__global__ __launch_bounds__(256, 2)
void lstm2_kern(const float* __restrict__ in_aux,
                const float* __restrict__ Wtoa1, const float* __restrict__ btoa1,
                const float* __restrict__ Wtoa2, const float* __restrict__ btoa2,
                const float* __restrict__ wsf, const u16* __restrict__ wpk,
                const u16* __restrict__ r1, int b_off, int ch_rows,
                float* __restrict__ out)
{
    __shared__ __align__(16) u16 sBihl[256 * 70];   // padded col stride 70
    __shared__ __align__(16) u16 sBhdh[32 * 70];
    __shared__ __align__(16) u16 sBhdl[32 * 70];
    __shared__ __align__(16) u16 hAh[2][16][72], hAl[2][16][72];
    __shared__ __align__(16) u16 hBh[2][16][72], hBl[2][16][72];
    const int tid = threadIdx.x;
    // one-time stage: Bih_l + head planes (frag layout, padded)
    for (int i = tid; i < 2048; i += 256) {
        int c = i >> 3, p = i & 7;
        *(u32x4*)(sBihl + c * 70 + p * 8) = *(const u32x4*)(wpk + W2IH_LO + c * 64 + p * 8);
    }
    {
        int c = tid >> 3, p = tid & 7;   // 256 jobs exactly
        *(u32x4*)(sBhdh + c * 70 + p * 8) = *(const u32x4*)(wpk + WHD_HI + c * 64 + p * 8);
        *(u32x4*)(sBhdl + c * 70 + p * 8) = *(const u32x4*)(wpk + WHD_LO + c * 64 + p * 8);
    }

    const int lane = tid & 63, wv = tid >> 6;
    const int q = lane >> 4, l15 = lane & 15;
    const int llocA = blockIdx.x * 32 + l15;
    const int llocB = llocA + 16;
    const int aRowA = b_off + llocA;
    const int aRowB = b_off + llocB;
    const int crowA = b_off + blockIdx.x * 32 + q * 4;
    const int crowB = crowA + 16;
    const int unit = wv * 16 + l15;

    bf16x8 Bih_h[4][2], Bhh_h[4][2], Bhh_l[4][2];
    float bias[4];
#pragma unroll
    for (int g = 0; g < 4; ++g) {
        const int col = g * 64 + unit;
#pragma unroll
        for (int kt = 0; kt < 2; ++kt) {
            Bih_h[g][kt] = *(const bf16x8*)(wpk + W2IH_HI + col * 64 + kt * 32 + q * 8);
            Bhh_h[g][kt] = *(const bf16x8*)(wpk + W2HH_HI + col * 64 + kt * 32 + q * 8);
            Bhh_l[g][kt] = *(const bf16x8*)(wpk + W2HH_LO + col * 64 + kt * 32 + q * 8);
        }
        bias[g] = wsf[256 + col];
    }
    const float bhd = (wv < 2) ? wsf[512 + wv * 16 + l15] : 0.f;
    const int hcol70 = (wv * 16 + l15) * 70;

    bf16x8 hfhA[2], hflA[2], hfhB[2], hflB[2];
    float cstA[4], cstB[4];
    {
        const float toaA = in_aux[(size_t)aRowA * 3 + 1];
        const float toaB = in_aux[(size_t)aRowB * 3 + 1];
#pragma unroll
        for (int kt = 0; kt < 2; ++kt) {
            u32 dhA[4], dlA[4], dhB[4], dlB[4];
#pragma unroll
            for (int p = 0; p < 4; ++p) {
                int k0 = kt * 32 + q * 8 + p * 2;
                float w0 = Wtoa2[k0], b0 = btoa2[k0], w1 = Wtoa2[k0 + 1], b1 = btoa2[k0 + 1];
                float ha = fmaf(toaA, w0, b0), hb = fmaf(toaA, w1, b1);
                u16 h1, l1, h2, l2; split2(ha, h1, l1); split2(hb, h2, l2);
                dhA[p] = ((u32)h2 << 16) | h1; dlA[p] = ((u32)l2 << 16) | l1;
                ha = fmaf(toaB, w0, b0); hb = fmaf(toaB, w1, b1);
                split2(ha, h1, l1); split2(hb, h2, l2);
                dhB[p] = ((u32)h2 << 16) | h1; dlB[p] = ((u32)l2 << 16) | l1;
            }
            __builtin_memcpy(&hfhA[kt], dhA, 16); __builtin_memcpy(&hflA[kt], dlA, 16);
            __builtin_memcpy(&hfhB[kt], dhB, 16); __builtin_memcpy(&hflB[kt], dlB, 16);
        }
#pragma unroll
        for (int r = 0; r < 4; ++r) {
            cstA[r] = fmaf(in_aux[(size_t)(crowA + r) * 3 + 1], Wtoa1[unit], btoa1[unit]);
            cstB[r] = fmaf(in_aux[(size_t)(crowB + r) * 3 + 1], Wtoa1[unit], btoa1[unit]);
        }
    }

    bf16x8 pxA[2], pxB[2];
#pragma unroll
    for (int kt = 0; kt < 2; ++kt) {
        pxA[kt] = *(const bf16x8*)(r1 + ((size_t)(kt * 4 + q) * ch_rows + llocA) * 8);
        pxB[kt] = *(const bf16x8*)(r1 + ((size_t)(kt * 4 + q) * ch_rows + llocB) * 8);
    }
    __syncthreads();   // staging complete (also covers first h-buffer use)

#pragma unroll 1
    for (int lev = 0; lev < NLEVS; ++lev) {
        const int buf = lev & 1;
        // gates: per-tile accumulation order identical to r12 (bit-exact)
        f32x4 CA[4], CB[4];
#pragma unroll
        for (int g = 0; g < 4; ++g) {
            f32x4 a = {bias[g], bias[g], bias[g], bias[g]};
            f32x4 b = {bias[g], bias[g], bias[g], bias[g]};
#pragma unroll
            for (int kt = 0; kt < 2; ++kt) {
                const bf16x8 wl = *(const bf16x8*)(sBihl + (g * 64 + unit) * 70 + (kt * 4 + q) * 8);
                a = MFMA(pxA[kt], Bih_h[g][kt], a);
                a = MFMA(pxA[kt], wl, a);
                a = MFMA(hfhA[kt], Bhh_h[g][kt], a);
                a = MFMA(hflA[kt], Bhh_h[g][kt], a);
                a = MFMA(hfhA[kt], Bhh_l[g][kt], a);
                b = MFMA(pxB[kt], Bih_h[g][kt], b);
                b = MFMA(pxB[kt], wl, b);
                b = MFMA(hfhB[kt], Bhh_h[g][kt], b);
                b = MFMA(hflB[kt], Bhh_h[g][kt], b);
                b = MFMA(hfhB[kt], Bhh_l[g][kt], b);
            }
            CA[g] = a;
            CB[g] = b;
        }
        // prefetch next-lev x (latency hides under act + LDS + barrier)
        if (lev < 59) {
#pragma unroll
            for (int kt = 0; kt < 2; ++kt) {
                pxA[kt] = *(const bf16x8*)(r1 + ((size_t)((lev + 1) * 8 + kt * 4 + q) * ch_rows + llocA) * 8);
                pxB[kt] = *(const bf16x8*)(r1 + ((size_t)((lev + 1) * 8 + kt * 4 + q) * ch_rows + llocB) * 8);
            }
        }
#pragma unroll
        for (int r = 0; r < 4; ++r) {
            float h = gate_act(CA[0][r], CA[1][r], CA[2][r], CA[3][r], cstA[r]);
            u16 hh_, hl_; split2(h, hh_, hl_);
            hAh[buf][q * 4 + r][unit] = hh_;
            hAl[buf][q * 4 + r][unit] = hl_;
            h = gate_act(CB[0][r], CB[1][r], CB[2][r], CB[3][r], cstB[r]);
            split2(h, hh_, hl_);
            hBh[buf][q * 4 + r][unit] = hh_;
            hBl[buf][q * 4 + r][unit] = hl_;
        }
        __syncthreads();
#pragma unroll
        for (int kt = 0; kt < 2; ++kt) {
            hfhA[kt] = *(const bf16x8*)&hAh[buf][l15][kt * 32 + q * 8];
            hflA[kt] = *(const bf16x8*)&hAl[buf][l15][kt * 32 + q * 8];
            hfhB[kt] = *(const bf16x8*)&hBh[buf][l15][kt * 32 + q * 8];
            hflB[kt] = *(const bf16x8*)&hBl[buf][l15][kt * 32 + q * 8];
        }
        // fused heads (waves 0/1), both tiles; order identical to r12 heads
        if (wv < 2) {
            f32x4 a = {bhd, bhd, bhd, bhd};
            f32x4 b = {bhd, bhd, bhd, bhd};
#pragma unroll
            for (int kt = 0; kt < 2; ++kt) {
                const bf16x8 Hh = *(const bf16x8*)(sBhdh + hcol70 + (kt * 4 + q) * 8);
                const bf16x8 Hl = *(const bf16x8*)(sBhdl + hcol70 + (kt * 4 + q) * 8);
                a = MFMA(hfhA[kt], Hh, a);
                a = MFMA(hfhA[kt], Hl, a);
                b = MFMA(hfhB[kt], Hh, b);
                b = MFMA(hfhB[kt], Hl, b);
            }
#pragma unroll
            for (int r = 0; r < 4; ++r) {
                const size_t gbA = (size_t)(crowA + r);
                const size_t gbB = (size_t)(crowB + r);
                if (wv == 0) {
                    out[MEM_OFF + (gbA * NLEVS + lev) * 16 + l15] = tanh_(a[r]);
                    out[MEM_OFF + (gbB * NLEVS + lev) * 16 + l15] = tanh_(b[r]);
                } else {
                    if (l15 < 4) {
                        out[(gbA * NLEVS + lev) * 4 + l15] = a[r];
                        out[(gbB * NLEVS + lev) * 4 + l15] = b[r];
                    } else if (l15 < 7 && lev == NLEVS - 1) {
                        out[SFC_OFF + gbA * 3 + (l15 - 4)] = a[r];
                        out[SFC_OFF + gbB * 3 + (l15 - 4)] = b[r];
                    }
                }
            }
        }
    }
}

extern "C" void kernel_launch(void* const* d_in, const int* in_sizes, int n_in,
                              void* d_out, int out_size, void* d_ws, size_t ws_size,
                              hipStream_t stream) {
    const float* in_main = (const float*)d_in[0];
    const float* in_aux  = (const float*)d_in[1];
    const float* in_mem  = (const float*)d_in[2];
    const float* Wsfc1   = (const float*)d_in[3];
    const float* bsfc1   = (const float*)d_in[4];
    const float* Wsfc2   = (const float*)d_in[5];
    const float* bsfc2   = (const float*)d_in[6];
    const float* Wtoa1   = (const float*)d_in[7];
    const float* btoa1   = (const float*)d_in[8];
    const float* Wtoa2   = (const float*)d_in[9];
    const float* btoa2   = (const float*)d_in[10];
    const float* W1ih    = (const float*)d_in[11];
    const float* W1hh    = (const float*)d_in[12];
    const float* b1ih    = (const float*)d_in[13];
    const float* b1hh    = (const float*)d_in[14];
    const float* W2ih    = (const float*)d_in[15];
    const float* W2hh    = (const float*)d_in[16];
    const float* b2ih    = (const float*)d_in[17];
    const float* b2hh    = (const float*)d_in[18];
    const float* Wlat    = (const float*)d_in[19];
    const float* blat    = (const float*)d_in[20];
    const float* Wout    = (const float*)d_in[21];
    const float* bout    = (const float*)d_in[22];
    const float* Wsfco   = (const float*)d_in[23];
    const float* bsfco   = (const float*)d_in[24];
    float* out           = (float*)d_out;

    float* wsf    = (float*)d_ws;
    u16*   wpk    = (u16*)((char*)d_ws + WPK_BYTE_OFF);
    u16*   rbase  = (u16*)((char*)d_ws + WS_R1_BYTE_OFF);

    setup_pack<<<235, 256, 0, stream>>>(W1ih, W1hh, W2ih, W2hh, Wlat, Wout, Wsfco,
                                        b1ih, b1hh, b2ih, b2hh, blat, bout, bsfco,
                                        wsf, wpk);

    const size_t avail = (ws_size > WS_R1_BYTE_OFF) ? ws_size - WS_R1_BYTE_OFF : 0;
    // per row: xb = 60*24*2 = 2880 B, r1 = 60*64*2 = 7680 B
    const size_t per_row = 2880 + 7680;
    size_t rows = avail / per_row;
    rows &= ~(size_t)31;
    if (rows > BATCH) rows = BATCH;
    if (rows < 32) rows = 32;

    for (int off = 0; off < BATCH; off += (int)rows) {
        int nr = (BATCH - off < (int)rows) ? (BATCH - off) : (int)rows;
        u16* xb = rbase;
        u16* r1 = rbase + (size_t)nr * NLEVS * 24;
        const int njobs = nr * NLEVS * 3;
        xcvt_kern<<<(njobs + 255) / 256, 256, 0, stream>>>(in_main, in_mem, xb, off, njobs);
        lstm1_kern<<<nr / 32, 256, 0, stream>>>(
            xb, in_aux, Wsfc1, bsfc1, Wsfc2, bsfc2, wsf, wpk, r1, off, nr);
        lstm2_kern<<<nr / 32, 256, 0, stream>>>(
            in_aux, Wtoa1, btoa1, Wtoa2, btoa2, wsf, wpk, r1, off, nr, out);
    }
}

// Round 15
// 325.483 us; speedup vs baseline: 1.4580x; 1.0839x over previous
//
#include <hip/hip_runtime.h>
#include <hip/hip_bf16.h>

typedef unsigned short u16;
typedef unsigned int u32;
typedef __attribute__((ext_vector_type(8))) short bf16x8;
typedef __attribute__((ext_vector_type(4))) float f32x4;
typedef __attribute__((ext_vector_type(4))) u32 u32x4;

#define BATCH 16384
#define NLEVS 60

#define SFC_OFF ((size_t)BATCH * NLEVS * 4)
#define MEM_OFF (SFC_OFF + (size_t)BATCH * 3)

// packed u16 plane offsets (in u16 units, from wpk) — layout validated r5-r14
#define W1IH_HI 0
#define W1IH_LO 8192
#define W1HH_HI 16384
#define W1HH_LO 32768
#define W2IH_HI 49152
#define W2IH_LO 65536
#define W2HH_HI 81920
#define W2HH_LO 98304
#define WHD_HI  114688
#define WHD_LO  116736

#define WPK_BYTE_OFF 4096
#define WS_R1_BYTE_OFF 262144

// gate prescale: i,f,o by -log2(e) (sigmoid), g by +2*log2(e) (tanh)
#define SIGK -1.4426950408889634f
#define TANK  2.8853900817779268f

#define MFMA(a, b, c) __builtin_amdgcn_mfma_f32_16x16x32_bf16((a), (b), (c), 0, 0, 0)

__device__ __forceinline__ float bf2f(u16 u) {
    union { u32 i; float f; } v; v.i = (u32)u << 16; return v.f;
}
__device__ __forceinline__ u16 f2bf(float f) {
    __hip_bfloat16 b = __float2bfloat16(f);
    u16 u; __builtin_memcpy(&u, &b, 2); return u;
}
__device__ __forceinline__ void split2(float w, u16& hi, u16& lo) {
    u16 h = f2bf(w);
    hi = h;
    lo = f2bf(w - bf2f(h));
}
__device__ __forceinline__ float tanh_(float x) {
    float ax = fabsf(x);
    float e  = __builtin_amdgcn_exp2f(-TANK * ax);
    float t  = (1.0f - e) * __builtin_amdgcn_rcpf(1.0f + e);
    return copysignf(t, x);
}

// Pack all weights to bf16 hi/lo planes with gate prescale; fuse biases and
// Wout@Wlat head (heads unscaled). Validated r5-r14.
__global__ void setup_pack(const float* __restrict__ W1ih, const float* __restrict__ W1hh,
                           const float* __restrict__ W2ih, const float* __restrict__ W2hh,
                           const float* __restrict__ Wlat, const float* __restrict__ Wout,
                           const float* __restrict__ Wsfco,
                           const float* __restrict__ b1ih, const float* __restrict__ b1hh,
                           const float* __restrict__ b2ih, const float* __restrict__ b2hh,
                           const float* __restrict__ blat, const float* __restrict__ bout,
                           const float* __restrict__ bsfco,
                           float* __restrict__ wsf, u16* __restrict__ wpk)
{
    int t = blockIdx.x * 256 + threadIdx.x;
    if (t < 256) {
        float sc = ((t >> 6) == 2) ? TANK : SIGK;
        wsf[t] = (b1ih[t] + b1hh[t]) * sc; return;
    }
    if (t < 512) {
        int j = t - 256;
        float sc = ((j >> 6) == 2) ? TANK : SIGK;
        wsf[256 + j] = (b2ih[j] + b2hh[j]) * sc; return;
    }
    if (t < 544) {
        int j = t - 512; float v;
        if (j < 16) v = blat[j];
        else if (j < 20) { v = bout[j - 16]; for (int m = 0; m < 16; ++m) v += Wout[(j - 16) * 16 + m] * blat[m]; }
        else if (j < 23) v = bsfco[j - 20];
        else v = 0.f;
        wsf[512 + j] = v; return;
    }
    int u = t - 544;
    float w; int hi_off, lo_off, idx, gate = -1;
    if (u < 8192) {
        int col = u >> 5, k = u & 31;
        w = (k < 20) ? W1ih[col * 20 + k] : 0.f;
        hi_off = W1IH_HI; lo_off = W1IH_LO; idx = u; gate = col >> 6;
    } else if (u < 24576) {
        idx = u - 8192; w = W1hh[idx]; hi_off = W1HH_HI; lo_off = W1HH_LO; gate = idx >> 12;
    } else if (u < 40960) {
        idx = u - 24576; w = W2ih[idx]; hi_off = W2IH_HI; lo_off = W2IH_LO; gate = idx >> 12;
    } else if (u < 57344) {
        idx = u - 40960; w = W2hh[idx]; hi_off = W2HH_HI; lo_off = W2HH_LO; gate = idx >> 12;
    } else if (u < 59392) {
        idx = u - 57344; int hc = idx >> 6, k = idx & 63;
        if (hc < 16) w = Wlat[hc * 64 + k];
        else if (hc < 20) { w = 0.f; for (int m = 0; m < 16; ++m) w += Wout[(hc - 16) * 16 + m] * Wlat[m * 64 + k]; }
        else if (hc < 23) w = Wsfco[(hc - 20) * 64 + k];
        else w = 0.f;
        hi_off = WHD_HI; lo_off = WHD_LO;
    } else return;
    if (gate >= 0) w *= (gate == 2) ? TANK : SIGK;
    u16 h_, l_; split2(w, h_, l_);
    wpk[hi_off + idx] = h_;
    wpk[lo_off + idx] = l_;
}

// Fused gate epilogue (prescaled pre-activations). Validated r8-r14.
__device__ __forceinline__ float gate_act(float si, float sf, float sg, float so, float& c) {
    float ei = __builtin_amdgcn_exp2f(si);
    float ef = __builtin_amdgcn_exp2f(sf);
    float eo = __builtin_amdgcn_exp2f(so);
    float eg = __builtin_amdgcn_exp2f(-fabsf(sg));
    float p2 = copysignf(1.f - eg, sg) * __builtin_amdgcn_rcpf((1.f + ei) * (1.f + eg));
    c = fmaf(__builtin_amdgcn_rcpf(1.f + ef), c, p2);
    float ec = __builtin_amdgcn_exp2f(-fabsf(TANK * c));
    return copysignf(1.f - ec, c) * __builtin_amdgcn_rcpf((1.f + eo) * (1.f + ec));
}

// ============ xcvt: pre-convert x to bf16 [row][lev][24] (k 20..23 = 0) ======
__global__ __launch_bounds__(256)
void xcvt_kern(const float* __restrict__ in_main, const float* __restrict__ in_mem,
               u16* __restrict__ xb, int b_off, int njobs)
{
    int t = blockIdx.x * 256 + threadIdx.x;
    if (t >= njobs) return;
    const int q = t % 3;
    const int rl = t / 3;
    const int lev = rl % NLEVS;
    const int row = rl / NLEVS;               // chunk-local
    const size_t mi = (size_t)(b_off + row) * NLEVS + lev;
    float v[8];
    if (q == 0) {
        float4 a = *(const float4*)(in_main + mi * 4);
        float4 b = *(const float4*)(in_mem + mi * 16);
        v[0]=a.x; v[1]=a.y; v[2]=a.z; v[3]=a.w; v[4]=b.x; v[5]=b.y; v[6]=b.z; v[7]=b.w;
    } else if (q == 1) {
        float4 a = *(const float4*)(in_mem + mi * 16 + 4);
        float4 b = *(const float4*)(in_mem + mi * 16 + 8);
        v[0]=a.x; v[1]=a.y; v[2]=a.z; v[3]=a.w; v[4]=b.x; v[5]=b.y; v[6]=b.z; v[7]=b.w;
    } else {
        float4 a = *(const float4*)(in_mem + mi * 16 + 12);
        v[0]=a.x; v[1]=a.y; v[2]=a.z; v[3]=a.w; v[4]=0; v[5]=0; v[6]=0; v[7]=0;
    }
    u32 d[4];
#pragma unroll
    for (int p = 0; p < 4; ++p)
        d[p] = ((u32)f2bf(v[p*2+1]) << 16) | f2bf(v[p*2]);
    *(u32x4*)(xb + ((size_t)row * NLEVS + lev) * 24 + q * 8) = *(const u32x4*)d;
}

// ============ Kernel 1: LSTM1 (reversed levels), 2 tiles/wave — UNCHANGED r12/r14
__global__ __launch_bounds__(256, 2)
void lstm1_kern(const u16* __restrict__ xb, const float* __restrict__ in_aux,
                const float* __restrict__ Wsfc1, const float* __restrict__ bsfc1,
                const float* __restrict__ Wsfc2, const float* __restrict__ bsfc2,
                const float* __restrict__ wsf, const u16* __restrict__ wpk,
                u16* __restrict__ r1, int b_off, int ch_rows)
{
    __shared__ __align__(16) u16 hAh[2][16][72], hAl[2][16][72];
    __shared__ __align__(16) u16 hBh[2][16][72], hBl[2][16][72];
    const int tid = threadIdx.x;
    const int lane = tid & 63, wv = tid >> 6;
    const int q = lane >> 4, l15 = lane & 15;
    const int llocA = blockIdx.x * 32 + l15;
    const int llocB = llocA + 16;
    const int aRowA = b_off + llocA;
    const int aRowB = b_off + llocB;
    const int crowA = b_off + blockIdx.x * 32 + q * 4;
    const int crowB = crowA + 16;
    const int unit = wv * 16 + l15;

    bf16x8 Bih_h[4], Bih_l[4], Bhh_h[4][2], Bhh_l[4][2];
    float bias[4];
#pragma unroll
    for (int g = 0; g < 4; ++g) {
        const int col = g * 64 + unit;
        Bih_h[g] = *(const bf16x8*)(wpk + W1IH_HI + col * 32 + q * 8);
        Bih_l[g] = *(const bf16x8*)(wpk + W1IH_LO + col * 32 + q * 8);
#pragma unroll
        for (int kt = 0; kt < 2; ++kt) {
            Bhh_h[g][kt] = *(const bf16x8*)(wpk + W1HH_HI + col * 64 + kt * 32 + q * 8);
            Bhh_l[g][kt] = *(const bf16x8*)(wpk + W1HH_LO + col * 64 + kt * 32 + q * 8);
        }
        bias[g] = wsf[col];
    }

    bf16x8 hfhA[2], hflA[2], hfhB[2], hflB[2];
    float cstA[4], cstB[4];

    {
        const float aA0 = in_aux[(size_t)aRowA * 3], aA1 = in_aux[(size_t)aRowA * 3 + 1], aA2 = in_aux[(size_t)aRowA * 3 + 2];
        const float aB0 = in_aux[(size_t)aRowB * 3], aB1 = in_aux[(size_t)aRowB * 3 + 1], aB2 = in_aux[(size_t)aRowB * 3 + 2];
#pragma unroll
        for (int kt = 0; kt < 2; ++kt) {
            u32 dhA[4], dlA[4], dhB[4], dlB[4];
#pragma unroll
            for (int p = 0; p < 4; ++p) {
                int k0 = kt * 32 + q * 8 + p * 2;
                float w0 = Wsfc1[k0*3], w1 = Wsfc1[k0*3+1], w2 = Wsfc1[k0*3+2], bb = bsfc1[k0];
                float w3 = Wsfc1[k0*3+3], w4 = Wsfc1[k0*3+4], w5 = Wsfc1[k0*3+5], bc = bsfc1[k0+1];
                float ha = tanh_(fmaf(aA0, w0, fmaf(aA1, w1, fmaf(aA2, w2, bb))));
                float hb = tanh_(fmaf(aA0, w3, fmaf(aA1, w4, fmaf(aA2, w5, bc))));
                u16 h1, l1, h2, l2; split2(ha, h1, l1); split2(hb, h2, l2);
                dhA[p] = ((u32)h2 << 16) | h1; dlA[p] = ((u32)l2 << 16) | l1;
                ha = tanh_(fmaf(aB0, w0, fmaf(aB1, w1, fmaf(aB2, w2, bb))));
                hb = tanh_(fmaf(aB0, w3, fmaf(aB1, w4, fmaf(aB2, w5, bc))));
                split2(ha, h1, l1); split2(hb, h2, l2);
                dhB[p] = ((u32)h2 << 16) | h1; dlB[p] = ((u32)l2 << 16) | l1;
            }
            __builtin_memcpy(&hfhA[kt], dhA, 16); __builtin_memcpy(&hflA[kt], dlA, 16);
            __builtin_memcpy(&hfhB[kt], dhB, 16); __builtin_memcpy(&hflB[kt], dlB, 16);
        }
#pragma unroll
        for (int r = 0; r < 4; ++r) {
            float w0 = Wsfc2[unit*3], w1 = Wsfc2[unit*3+1], w2 = Wsfc2[unit*3+2], bb = bsfc2[unit];
            const size_t grA = (size_t)(crowA + r) * 3;
            cstA[r] = tanh_(fmaf(in_aux[grA], w0, fmaf(in_aux[grA+1], w1, fmaf(in_aux[grA+2], w2, bb))));
            const size_t grB = (size_t)(crowB + r) * 3;
            cstB[r] = tanh_(fmaf(in_aux[grB], w0, fmaf(in_aux[grB+1], w1, fmaf(in_aux[grB+2], w2, bb))));
        }
    }

    bf16x8 axA = {}, axB = {};
    if (q < 3) {
        axA = *(const bf16x8*)(xb + ((size_t)llocA * NLEVS + 59) * 24 + q * 8);
        axB = *(const bf16x8*)(xb + ((size_t)llocB * NLEVS + 59) * 24 + q * 8);
    }

#pragma unroll 1
    for (int t = 0; t < NLEVS; ++t) {
        const int lev = 59 - t;
        const int buf = t & 1;
        bf16x8 xA = axA, xB = axB;
        if (t < 59 && q < 3) {
            axA = *(const bf16x8*)(xb + ((size_t)llocA * NLEVS + (lev - 1)) * 24 + q * 8);
            axB = *(const bf16x8*)(xb + ((size_t)llocB * NLEVS + (lev - 1)) * 24 + q * 8);
        }
        f32x4 CA[4], CB[4];
#pragma unroll
        for (int g = 0; g < 4; ++g) {
            f32x4 a = {bias[g], bias[g], bias[g], bias[g]};
            a = MFMA(xA, Bih_h[g], a);
            a = MFMA(xA, Bih_l[g], a);
#pragma unroll
            for (int kt = 0; kt < 2; ++kt) {
                a = MFMA(hfhA[kt], Bhh_h[g][kt], a);
                a = MFMA(hflA[kt], Bhh_h[g][kt], a);
                a = MFMA(hfhA[kt], Bhh_l[g][kt], a);
            }
            CA[g] = a;
            f32x4 b = {bias[g], bias[g], bias[g], bias[g]};
            b = MFMA(xB, Bih_h[g], b);
            b = MFMA(xB, Bih_l[g], b);
#pragma unroll
            for (int kt = 0; kt < 2; ++kt) {
                b = MFMA(hfhB[kt], Bhh_h[g][kt], b);
                b = MFMA(hflB[kt], Bhh_h[g][kt], b);
                b = MFMA(hfhB[kt], Bhh_l[g][kt], b);
            }
            CB[g] = b;
        }
#pragma unroll
        for (int r = 0; r < 4; ++r) {
            float h = gate_act(CA[0][r], CA[1][r], CA[2][r], CA[3][r], cstA[r]);
            u16 hh_, hl_; split2(h, hh_, hl_);
            hAh[buf][q * 4 + r][unit] = hh_;
            hAl[buf][q * 4 + r][unit] = hl_;
            h = gate_act(CB[0][r], CB[1][r], CB[2][r], CB[3][r], cstB[r]);
            split2(h, hh_, hl_);
            hBh[buf][q * 4 + r][unit] = hh_;
            hBl[buf][q * 4 + r][unit] = hl_;
        }
        __syncthreads();
#pragma unroll
        for (int kt = 0; kt < 2; ++kt) {
            hfhA[kt] = *(const bf16x8*)&hAh[buf][l15][kt * 32 + q * 8];
            hflA[kt] = *(const bf16x8*)&hAl[buf][l15][kt * 32 + q * 8];
            hfhB[kt] = *(const bf16x8*)&hBh[buf][l15][kt * 32 + q * 8];
            hflB[kt] = *(const bf16x8*)&hBl[buf][l15][kt * 32 + q * 8];
            u32x4 svA; __builtin_memcpy(&svA, &hfhA[kt], 16);
            u32x4 svB; __builtin_memcpy(&svB, &hfhB[kt], 16);
            *(u32x4*)(r1 + ((size_t)(lev * 8 + kt * 4 + q) * ch_rows + llocA) * 8) = svA;
            *(u32x4*)(r1 + ((size_t)(lev * 8 + kt * 4 + q) * ch_rows + llocB) * 8) = svB;
        }
    }
}

// ============ Kernel 2: LSTM2 + fused heads, 2 tiles/wave ====================
// W2ih single-bf16 (lo dropped: its operand r1 is already bf16-quantized, so
// the lo term is below the input noise floor). W2hh + h stay hi/lo (recurrent
// fidelity). Heads hi/lo via LDS. Pointer-bumped r1 prefetch.
__global__ __launch_bounds__(256, 2)
void lstm2_kern(const float* __restrict__ in_aux,
                const float* __restrict__ Wtoa1, const float* __restrict__ btoa1,
                const float* __restrict__ Wtoa2, const float* __restrict__ btoa2,
                const float* __restrict__ wsf, const u16* __restrict__ wpk,
                const u16* __restrict__ r1, int b_off, int ch_rows,
                float* __restrict__ out)
{
    __shared__ __align__(16) u16 sBhdh[32 * 70];
    __shared__ __align__(16) u16 sBhdl[32 * 70];
    __shared__ __align__(16) u16 hAh[2][16][72], hAl[2][16][72];
    __shared__ __align__(16) u16 hBh[2][16][72], hBl[2][16][72];
    const int tid = threadIdx.x;
    {
        int c = tid >> 3, p = tid & 7;   // 256 jobs exactly
        *(u32x4*)(sBhdh + c * 70 + p * 8) = *(const u32x4*)(wpk + WHD_HI + c * 64 + p * 8);
        *(u32x4*)(sBhdl + c * 70 + p * 8) = *(const u32x4*)(wpk + WHD_LO + c * 64 + p * 8);
    }

    const int lane = tid & 63, wv = tid >> 6;
    const int q = lane >> 4, l15 = lane & 15;
    const int llocA = blockIdx.x * 32 + l15;
    const int llocB = llocA + 16;
    const int aRowA = b_off + llocA;
    const int aRowB = b_off + llocB;
    const int crowA = b_off + blockIdx.x * 32 + q * 4;
    const int crowB = crowA + 16;
    const int unit = wv * 16 + l15;

    bf16x8 Bih_h[4][2], Bhh_h[4][2], Bhh_l[4][2];
    float bias[4];
#pragma unroll
    for (int g = 0; g < 4; ++g) {
        const int col = g * 64 + unit;
#pragma unroll
        for (int kt = 0; kt < 2; ++kt) {
            Bih_h[g][kt] = *(const bf16x8*)(wpk + W2IH_HI + col * 64 + kt * 32 + q * 8);
            Bhh_h[g][kt] = *(const bf16x8*)(wpk + W2HH_HI + col * 64 + kt * 32 + q * 8);
            Bhh_l[g][kt] = *(const bf16x8*)(wpk + W2HH_LO + col * 64 + kt * 32 + q * 8);
        }
        bias[g] = wsf[256 + col];
    }
    const float bhd = (wv < 2) ? wsf[512 + wv * 16 + l15] : 0.f;
    const int hcol70 = (wv * 16 + l15) * 70;

    bf16x8 hfhA[2], hflA[2], hfhB[2], hflB[2];
    float cstA[4], cstB[4];
    {
        const float toaA = in_aux[(size_t)aRowA * 3 + 1];
        const float toaB = in_aux[(size_t)aRowB * 3 + 1];
#pragma unroll
        for (int kt = 0; kt < 2; ++kt) {
            u32 dhA[4], dlA[4], dhB[4], dlB[4];
#pragma unroll
            for (int p = 0; p < 4; ++p) {
                int k0 = kt * 32 + q * 8 + p * 2;
                float w0 = Wtoa2[k0], b0 = btoa2[k0], w1 = Wtoa2[k0 + 1], b1 = btoa2[k0 + 1];
                float ha = fmaf(toaA, w0, b0), hb = fmaf(toaA, w1, b1);
                u16 h1, l1, h2, l2; split2(ha, h1, l1); split2(hb, h2, l2);
                dhA[p] = ((u32)h2 << 16) | h1; dlA[p] = ((u32)l2 << 16) | l1;
                ha = fmaf(toaB, w0, b0); hb = fmaf(toaB, w1, b1);
                split2(ha, h1, l1); split2(hb, h2, l2);
                dhB[p] = ((u32)h2 << 16) | h1; dlB[p] = ((u32)l2 << 16) | l1;
            }
            __builtin_memcpy(&hfhA[kt], dhA, 16); __builtin_memcpy(&hflA[kt], dlA, 16);
            __builtin_memcpy(&hfhB[kt], dhB, 16); __builtin_memcpy(&hflB[kt], dlB, 16);
        }
#pragma unroll
        for (int r = 0; r < 4; ++r) {
            cstA[r] = fmaf(in_aux[(size_t)(crowA + r) * 3 + 1], Wtoa1[unit], btoa1[unit]);
            cstB[r] = fmaf(in_aux[(size_t)(crowB + r) * 3 + 1], Wtoa1[unit], btoa1[unit]);
        }
    }

    // pointer-bumped r1 prefetch (plane stride per lev = 8 planes)
    const size_t lstep = (size_t)8 * ch_rows * 8;
    const u16* rA0 = r1 + ((size_t)(q)     * ch_rows + llocA) * 8;
    const u16* rA1 = r1 + ((size_t)(4 + q) * ch_rows + llocA) * 8;
    const u16* rB0 = r1 + ((size_t)(q)     * ch_rows + llocB) * 8;
    const u16* rB1 = r1 + ((size_t)(4 + q) * ch_rows + llocB) * 8;
    bf16x8 pxA[2], pxB[2];
    pxA[0] = *(const bf16x8*)rA0; pxA[1] = *(const bf16x8*)rA1;
    pxB[0] = *(const bf16x8*)rB0; pxB[1] = *(const bf16x8*)rB1;
    __syncthreads();   // staging complete

#pragma unroll 1
    for (int lev = 0; lev < NLEVS; ++lev) {
        const int buf = lev & 1;
        f32x4 CA[4], CB[4];
#pragma unroll
        for (int g = 0; g < 4; ++g) {
            f32x4 a = {bias[g], bias[g], bias[g], bias[g]};
            f32x4 b = {bias[g], bias[g], bias[g], bias[g]};
#pragma unroll
            for (int kt = 0; kt < 2; ++kt) {
                a = MFMA(pxA[kt], Bih_h[g][kt], a);
                a = MFMA(hfhA[kt], Bhh_h[g][kt], a);
                a = MFMA(hflA[kt], Bhh_h[g][kt], a);
                a = MFMA(hfhA[kt], Bhh_l[g][kt], a);
                b = MFMA(pxB[kt], Bih_h[g][kt], b);
                b = MFMA(hfhB[kt], Bhh_h[g][kt], b);
                b = MFMA(hflB[kt], Bhh_h[g][kt], b);
                b = MFMA(hfhB[kt], Bhh_l[g][kt], b);
            }
            CA[g] = a;
            CB[g] = b;
        }
        // prefetch next-lev x (pointer bump; latency hides under act+LDS+barrier)
        if (lev < 59) {
            rA0 += lstep; rA1 += lstep; rB0 += lstep; rB1 += lstep;
            pxA[0] = *(const bf16x8*)rA0; pxA[1] = *(const bf16x8*)rA1;
            pxB[0] = *(const bf16x8*)rB0; pxB[1] = *(const bf16x8*)rB1;
        }
#pragma unroll
        for (int r = 0; r < 4; ++r) {
            float h = gate_act(CA[0][r], CA[1][r], CA[2][r], CA[3][r], cstA[r]);
            u16 hh_, hl_; split2(h, hh_, hl_);
            hAh[buf][q * 4 + r][unit] = hh_;
            hAl[buf][q * 4 + r][unit] = hl_;
            h = gate_act(CB[0][r], CB[1][r], CB[2][r], CB[3][r], cstB[r]);
            split2(h, hh_, hl_);
            hBh[buf][q * 4 + r][unit] = hh_;
            hBl[buf][q * 4 + r][unit] = hl_;
        }
        __syncthreads();
#pragma unroll
        for (int kt = 0; kt < 2; ++kt) {
            hfhA[kt] = *(const bf16x8*)&hAh[buf][l15][kt * 32 + q * 8];
            hflA[kt] = *(const bf16x8*)&hAl[buf][l15][kt * 32 + q * 8];
            hfhB[kt] = *(const bf16x8*)&hBh[buf][l15][kt * 32 + q * 8];
            hflB[kt] = *(const bf16x8*)&hBl[buf][l15][kt * 32 + q * 8];
        }
        // fused heads (waves 0/1), both tiles; hi/lo — unchanged from r14
        if (wv < 2) {
            f32x4 a = {bhd, bhd, bhd, bhd};
            f32x4 b = {bhd, bhd, bhd, bhd};
#pragma unroll
            for (int kt = 0; kt < 2; ++kt) {
                const bf16x8 Hh = *(const bf16x8*)(sBhdh + hcol70 + (kt * 4 + q) * 8);
                const bf16x8 Hl = *(const bf16x8*)(sBhdl + hcol70 + (kt * 4 + q) * 8);
                a = MFMA(hfhA[kt], Hh, a);
                a = MFMA(hfhA[kt], Hl, a);
                b = MFMA(hfhB[kt], Hh, b);
                b = MFMA(hfhB[kt], Hl, b);
            }
#pragma unroll
            for (int r = 0; r < 4; ++r) {
                const size_t gbA = (size_t)(crowA + r);
                const size_t gbB = (size_t)(crowB + r);
                if (wv == 0) {
                    out[MEM_OFF + (gbA * NLEVS + lev) * 16 + l15] = tanh_(a[r]);
                    out[MEM_OFF + (gbB * NLEVS + lev) * 16 + l15] = tanh_(b[r]);
                } else {
                    if (l15 < 4) {
                        out[(gbA * NLEVS + lev) * 4 + l15] = a[r];
                        out[(gbB * NLEVS + lev) * 4 + l15] = b[r];
                    } else if (l15 < 7 && lev == NLEVS - 1) {
                        out[SFC_OFF + gbA * 3 + (l15 - 4)] = a[r];
                        out[SFC_OFF + gbB * 3 + (l15 - 4)] = b[r];
                    }
                }
            }
        }
    }
}

extern "C" void kernel_launch(void* const* d_in, const int* in_sizes, int n_in,
                              void* d_out, int out_size, void* d_ws, size_t ws_size,
                              hipStream_t stream) {
    const float* in_main = (const float*)d_in[0];
    const float* in_aux  = (const float*)d_in[1];
    const float* in_mem  = (const float*)d_in[2];
    const float* Wsfc1   = (const float*)d_in[3];
    const float* bsfc1   = (const float*)d_in[4];
    const float* Wsfc2   = (const float*)d_in[5];
    const float* bsfc2   = (const float*)d_in[6];
    const float* Wtoa1   = (const float*)d_in[7];
    const float* btoa1   = (const float*)d_in[8];
    const float* Wtoa2   = (const float*)d_in[9];
    const float* btoa2   = (const float*)d_in[10];
    const float* W1ih    = (const float*)d_in[11];
    const float* W1hh    = (const float*)d_in[12];
    const float* b1ih    = (const float*)d_in[13];
    const float* b1hh    = (const float*)d_in[14];
    const float* W2ih    = (const float*)d_in[15];
    const float* W2hh    = (const float*)d_in[16];
    const float* b2ih    = (const float*)d_in[17];
    const float* b2hh    = (const float*)d_in[18];
    const float* Wlat    = (const float*)d_in[19];
    const float* blat    = (const float*)d_in[20];
    const float* Wout    = (const float*)d_in[21];
    const float* bout    = (const float*)d_in[22];
    const float* Wsfco   = (const float*)d_in[23];
    const float* bsfco   = (const float*)d_in[24];
    float* out           = (float*)d_out;

    float* wsf    = (float*)d_ws;
    u16*   wpk    = (u16*)((char*)d_ws + WPK_BYTE_OFF);
    u16*   rbase  = (u16*)((char*)d_ws + WS_R1_BYTE_OFF);

    setup_pack<<<235, 256, 0, stream>>>(W1ih, W1hh, W2ih, W2hh, Wlat, Wout, Wsfco,
                                        b1ih, b1hh, b2ih, b2hh, blat, bout, bsfco,
                                        wsf, wpk);

    const size_t avail = (ws_size > WS_R1_BYTE_OFF) ? ws_size - WS_R1_BYTE_OFF : 0;
    // per row: xb = 60*24*2 = 2880 B, r1 = 60*64*2 = 7680 B
    const size_t per_row = 2880 + 7680;
    size_t rows = avail / per_row;
    rows &= ~(size_t)31;
    if (rows > BATCH) rows = BATCH;
    if (rows < 32) rows = 32;

    for (int off = 0; off < BATCH; off += (int)rows) {
        int nr = (BATCH - off < (int)rows) ? (BATCH - off) : (int)rows;
        u16* xb = rbase;
        u16* r1 = rbase + (size_t)nr * NLEVS * 24;
        const int njobs = nr * NLEVS * 3;
        xcvt_kern<<<(njobs + 255) / 256, 256, 0, stream>>>(in_main, in_mem, xb, off, njobs);
        lstm1_kern<<<nr / 32, 256, 0, stream>>>(
            xb, in_aux, Wsfc1, bsfc1, Wsfc2, bsfc2, wsf, wpk, r1, off, nr);
        lstm2_kern<<<nr / 32, 256, 0, stream>>>(
            in_aux, Wtoa1, btoa1, Wtoa2, btoa2, wsf, wpk, r1, off, nr, out);
    }
}

// Round 16
// 290.833 us; speedup vs baseline: 1.6317x; 1.1191x over previous
//
#include <hip/hip_runtime.h>
#include <hip/hip_bf16.h>

typedef unsigned short u16;
typedef unsigned int u32;
typedef __attribute__((ext_vector_type(8))) short bf16x8;
typedef __attribute__((ext_vector_type(4))) float f32x4;
typedef __attribute__((ext_vector_type(4))) u32 u32x4;

#define BATCH 16384
#define NLEVS 60

#define SFC_OFF ((size_t)BATCH * NLEVS * 4)
#define MEM_OFF (SFC_OFF + (size_t)BATCH * 3)

// packed u16 plane offsets (in u16 units, from wpk) — layout validated r5-r15
#define W1IH_HI 0
#define W1IH_LO 8192
#define W1HH_HI 16384
#define W1HH_LO 32768
#define W2IH_HI 49152
#define W2IH_LO 65536
#define W2HH_HI 81920
#define W2HH_LO 98304
#define WHD_HI  114688
#define WHD_LO  116736

#define WPK_BYTE_OFF 4096
#define WS_R1_BYTE_OFF 262144

// gate prescale: i,f,o by -log2(e) (sigmoid), g by +2*log2(e) (tanh)
#define SIGK -1.4426950408889634f
#define TANK  2.8853900817779268f

#define MFMA(a, b, c) __builtin_amdgcn_mfma_f32_16x16x32_bf16((a), (b), (c), 0, 0, 0)

__device__ __forceinline__ float bf2f(u16 u) {
    union { u32 i; float f; } v; v.i = (u32)u << 16; return v.f;
}
__device__ __forceinline__ u16 f2bf(float f) {
    __hip_bfloat16 b = __float2bfloat16(f);
    u16 u; __builtin_memcpy(&u, &b, 2); return u;
}
__device__ __forceinline__ void split2(float w, u16& hi, u16& lo) {
    u16 h = f2bf(w);
    hi = h;
    lo = f2bf(w - bf2f(h));
}
__device__ __forceinline__ float tanh_(float x) {
    float ax = fabsf(x);
    float e  = __builtin_amdgcn_exp2f(-TANK * ax);
    float t  = (1.0f - e) * __builtin_amdgcn_rcpf(1.0f + e);
    return copysignf(t, x);
}

// Pack all weights to bf16 hi/lo planes with gate prescale; fuse biases and
// Wout@Wlat head (heads unscaled). Validated r5-r15.
__global__ void setup_pack(const float* __restrict__ W1ih, const float* __restrict__ W1hh,
                           const float* __restrict__ W2ih, const float* __restrict__ W2hh,
                           const float* __restrict__ Wlat, const float* __restrict__ Wout,
                           const float* __restrict__ Wsfco,
                           const float* __restrict__ b1ih, const float* __restrict__ b1hh,
                           const float* __restrict__ b2ih, const float* __restrict__ b2hh,
                           const float* __restrict__ blat, const float* __restrict__ bout,
                           const float* __restrict__ bsfco,
                           float* __restrict__ wsf, u16* __restrict__ wpk)
{
    int t = blockIdx.x * 256 + threadIdx.x;
    if (t < 256) {
        float sc = ((t >> 6) == 2) ? TANK : SIGK;
        wsf[t] = (b1ih[t] + b1hh[t]) * sc; return;
    }
    if (t < 512) {
        int j = t - 256;
        float sc = ((j >> 6) == 2) ? TANK : SIGK;
        wsf[256 + j] = (b2ih[j] + b2hh[j]) * sc; return;
    }
    if (t < 544) {
        int j = t - 512; float v;
        if (j < 16) v = blat[j];
        else if (j < 20) { v = bout[j - 16]; for (int m = 0; m < 16; ++m) v += Wout[(j - 16) * 16 + m] * blat[m]; }
        else if (j < 23) v = bsfco[j - 20];
        else v = 0.f;
        wsf[512 + j] = v; return;
    }
    int u = t - 544;
    float w; int hi_off, lo_off, idx, gate = -1;
    if (u < 8192) {
        int col = u >> 5, k = u & 31;
        w = (k < 20) ? W1ih[col * 20 + k] : 0.f;
        hi_off = W1IH_HI; lo_off = W1IH_LO; idx = u; gate = col >> 6;
    } else if (u < 24576) {
        idx = u - 8192; w = W1hh[idx]; hi_off = W1HH_HI; lo_off = W1HH_LO; gate = idx >> 12;
    } else if (u < 40960) {
        idx = u - 24576; w = W2ih[idx]; hi_off = W2IH_HI; lo_off = W2IH_LO; gate = idx >> 12;
    } else if (u < 57344) {
        idx = u - 40960; w = W2hh[idx]; hi_off = W2HH_HI; lo_off = W2HH_LO; gate = idx >> 12;
    } else if (u < 59392) {
        idx = u - 57344; int hc = idx >> 6, k = idx & 63;
        if (hc < 16) w = Wlat[hc * 64 + k];
        else if (hc < 20) { w = 0.f; for (int m = 0; m < 16; ++m) w += Wout[(hc - 16) * 16 + m] * Wlat[m * 64 + k]; }
        else if (hc < 23) w = Wsfco[(hc - 20) * 64 + k];
        else w = 0.f;
        hi_off = WHD_HI; lo_off = WHD_LO;
    } else return;
    if (gate >= 0) w *= (gate == 2) ? TANK : SIGK;
    u16 h_, l_; split2(w, h_, l_);
    wpk[hi_off + idx] = h_;
    wpk[lo_off + idx] = l_;
}

// Fused gate epilogue (prescaled pre-activations). Validated r8-r15.
__device__ __forceinline__ float gate_act(float si, float sf, float sg, float so, float& c) {
    float ei = __builtin_amdgcn_exp2f(si);
    float ef = __builtin_amdgcn_exp2f(sf);
    float eo = __builtin_amdgcn_exp2f(so);
    float eg = __builtin_amdgcn_exp2f(-fabsf(sg));
    float p2 = copysignf(1.f - eg, sg) * __builtin_amdgcn_rcpf((1.f + ei) * (1.f + eg));
    c = fmaf(__builtin_amdgcn_rcpf(1.f + ef), c, p2);
    float ec = __builtin_amdgcn_exp2f(-fabsf(TANK * c));
    return copysignf(1.f - ec, c) * __builtin_amdgcn_rcpf((1.f + eo) * (1.f + ec));
}

// ============ xcvt: pre-convert x to bf16 [row][lev][24] (k 20..23 = 0) ======
__global__ __launch_bounds__(256)
void xcvt_kern(const float* __restrict__ in_main, const float* __restrict__ in_mem,
               u16* __restrict__ xb, int b_off, int njobs)
{
    int t = blockIdx.x * 256 + threadIdx.x;
    if (t >= njobs) return;
    const int q = t % 3;
    const int rl = t / 3;
    const int lev = rl % NLEVS;
    const int row = rl / NLEVS;               // chunk-local
    const size_t mi = (size_t)(b_off + row) * NLEVS + lev;
    float v[8];
    if (q == 0) {
        float4 a = *(const float4*)(in_main + mi * 4);
        float4 b = *(const float4*)(in_mem + mi * 16);
        v[0]=a.x; v[1]=a.y; v[2]=a.z; v[3]=a.w; v[4]=b.x; v[5]=b.y; v[6]=b.z; v[7]=b.w;
    } else if (q == 1) {
        float4 a = *(const float4*)(in_mem + mi * 16 + 4);
        float4 b = *(const float4*)(in_mem + mi * 16 + 8);
        v[0]=a.x; v[1]=a.y; v[2]=a.z; v[3]=a.w; v[4]=b.x; v[5]=b.y; v[6]=b.z; v[7]=b.w;
    } else {
        float4 a = *(const float4*)(in_mem + mi * 16 + 12);
        v[0]=a.x; v[1]=a.y; v[2]=a.z; v[3]=a.w; v[4]=0; v[5]=0; v[6]=0; v[7]=0;
    }
    u32 d[4];
#pragma unroll
    for (int p = 0; p < 4; ++p)
        d[p] = ((u32)f2bf(v[p*2+1]) << 16) | f2bf(v[p*2]);
    *(u32x4*)(xb + ((size_t)row * NLEVS + lev) * 24 + q * 8) = *(const u32x4*)d;
}

// ============ Kernel 1: LSTM1 (reversed levels), 2 tiles/wave ================
// CHANGE vs r15: recurrent h is single-bf16 (hfl/hAl/hBl dropped). All weight
// hi/lo terms retained (x: Bih_h+Bih_l; h: Bhh_h+Bhh_l applied to hfh).
__global__ __launch_bounds__(256, 2)
void lstm1_kern(const u16* __restrict__ xb, const float* __restrict__ in_aux,
                const float* __restrict__ Wsfc1, const float* __restrict__ bsfc1,
                const float* __restrict__ Wsfc2, const float* __restrict__ bsfc2,
                const float* __restrict__ wsf, const u16* __restrict__ wpk,
                u16* __restrict__ r1, int b_off, int ch_rows)
{
    __shared__ __align__(16) u16 hAh[2][16][72];
    __shared__ __align__(16) u16 hBh[2][16][72];
    const int tid = threadIdx.x;
    const int lane = tid & 63, wv = tid >> 6;
    const int q = lane >> 4, l15 = lane & 15;
    const int llocA = blockIdx.x * 32 + l15;
    const int llocB = llocA + 16;
    const int aRowA = b_off + llocA;
    const int aRowB = b_off + llocB;
    const int crowA = b_off + blockIdx.x * 32 + q * 4;
    const int crowB = crowA + 16;
    const int unit = wv * 16 + l15;

    bf16x8 Bih_h[4], Bih_l[4], Bhh_h[4][2], Bhh_l[4][2];
    float bias[4];
#pragma unroll
    for (int g = 0; g < 4; ++g) {
        const int col = g * 64 + unit;
        Bih_h[g] = *(const bf16x8*)(wpk + W1IH_HI + col * 32 + q * 8);
        Bih_l[g] = *(const bf16x8*)(wpk + W1IH_LO + col * 32 + q * 8);
#pragma unroll
        for (int kt = 0; kt < 2; ++kt) {
            Bhh_h[g][kt] = *(const bf16x8*)(wpk + W1HH_HI + col * 64 + kt * 32 + q * 8);
            Bhh_l[g][kt] = *(const bf16x8*)(wpk + W1HH_LO + col * 64 + kt * 32 + q * 8);
        }
        bias[g] = wsf[col];
    }

    bf16x8 hfhA[2], hfhB[2];
    float cstA[4], cstB[4];

    {
        const float aA0 = in_aux[(size_t)aRowA * 3], aA1 = in_aux[(size_t)aRowA * 3 + 1], aA2 = in_aux[(size_t)aRowA * 3 + 2];
        const float aB0 = in_aux[(size_t)aRowB * 3], aB1 = in_aux[(size_t)aRowB * 3 + 1], aB2 = in_aux[(size_t)aRowB * 3 + 2];
#pragma unroll
        for (int kt = 0; kt < 2; ++kt) {
            u32 dhA[4], dhB[4];
#pragma unroll
            for (int p = 0; p < 4; ++p) {
                int k0 = kt * 32 + q * 8 + p * 2;
                float w0 = Wsfc1[k0*3], w1 = Wsfc1[k0*3+1], w2 = Wsfc1[k0*3+2], bb = bsfc1[k0];
                float w3 = Wsfc1[k0*3+3], w4 = Wsfc1[k0*3+4], w5 = Wsfc1[k0*3+5], bc = bsfc1[k0+1];
                float ha = tanh_(fmaf(aA0, w0, fmaf(aA1, w1, fmaf(aA2, w2, bb))));
                float hb = tanh_(fmaf(aA0, w3, fmaf(aA1, w4, fmaf(aA2, w5, bc))));
                dhA[p] = ((u32)f2bf(hb) << 16) | f2bf(ha);
                ha = tanh_(fmaf(aB0, w0, fmaf(aB1, w1, fmaf(aB2, w2, bb))));
                hb = tanh_(fmaf(aB0, w3, fmaf(aB1, w4, fmaf(aB2, w5, bc))));
                dhB[p] = ((u32)f2bf(hb) << 16) | f2bf(ha);
            }
            __builtin_memcpy(&hfhA[kt], dhA, 16);
            __builtin_memcpy(&hfhB[kt], dhB, 16);
        }
#pragma unroll
        for (int r = 0; r < 4; ++r) {
            float w0 = Wsfc2[unit*3], w1 = Wsfc2[unit*3+1], w2 = Wsfc2[unit*3+2], bb = bsfc2[unit];
            const size_t grA = (size_t)(crowA + r) * 3;
            cstA[r] = tanh_(fmaf(in_aux[grA], w0, fmaf(in_aux[grA+1], w1, fmaf(in_aux[grA+2], w2, bb))));
            const size_t grB = (size_t)(crowB + r) * 3;
            cstB[r] = tanh_(fmaf(in_aux[grB], w0, fmaf(in_aux[grB+1], w1, fmaf(in_aux[grB+2], w2, bb))));
        }
    }

    bf16x8 axA = {}, axB = {};
    if (q < 3) {
        axA = *(const bf16x8*)(xb + ((size_t)llocA * NLEVS + 59) * 24 + q * 8);
        axB = *(const bf16x8*)(xb + ((size_t)llocB * NLEVS + 59) * 24 + q * 8);
    }

#pragma unroll 1
    for (int t = 0; t < NLEVS; ++t) {
        const int lev = 59 - t;
        const int buf = t & 1;
        bf16x8 xA = axA, xB = axB;
        if (t < 59 && q < 3) {
            axA = *(const bf16x8*)(xb + ((size_t)llocA * NLEVS + (lev - 1)) * 24 + q * 8);
            axB = *(const bf16x8*)(xb + ((size_t)llocB * NLEVS + (lev - 1)) * 24 + q * 8);
        }
        f32x4 CA[4], CB[4];
#pragma unroll
        for (int g = 0; g < 4; ++g) {
            f32x4 a = {bias[g], bias[g], bias[g], bias[g]};
            a = MFMA(xA, Bih_h[g], a);
            a = MFMA(xA, Bih_l[g], a);
#pragma unroll
            for (int kt = 0; kt < 2; ++kt) {
                a = MFMA(hfhA[kt], Bhh_h[g][kt], a);
                a = MFMA(hfhA[kt], Bhh_l[g][kt], a);
            }
            CA[g] = a;
            f32x4 b = {bias[g], bias[g], bias[g], bias[g]};
            b = MFMA(xB, Bih_h[g], b);
            b = MFMA(xB, Bih_l[g], b);
#pragma unroll
            for (int kt = 0; kt < 2; ++kt) {
                b = MFMA(hfhB[kt], Bhh_h[g][kt], b);
                b = MFMA(hfhB[kt], Bhh_l[g][kt], b);
            }
            CB[g] = b;
        }
#pragma unroll
        for (int r = 0; r < 4; ++r) {
            float h = gate_act(CA[0][r], CA[1][r], CA[2][r], CA[3][r], cstA[r]);
            hAh[buf][q * 4 + r][unit] = f2bf(h);
            h = gate_act(CB[0][r], CB[1][r], CB[2][r], CB[3][r], cstB[r]);
            hBh[buf][q * 4 + r][unit] = f2bf(h);
        }
        __syncthreads();
#pragma unroll
        for (int kt = 0; kt < 2; ++kt) {
            hfhA[kt] = *(const bf16x8*)&hAh[buf][l15][kt * 32 + q * 8];
            hfhB[kt] = *(const bf16x8*)&hBh[buf][l15][kt * 32 + q * 8];
            u32x4 svA; __builtin_memcpy(&svA, &hfhA[kt], 16);
            u32x4 svB; __builtin_memcpy(&svB, &hfhB[kt], 16);
            *(u32x4*)(r1 + ((size_t)(lev * 8 + kt * 4 + q) * ch_rows + llocA) * 8) = svA;
            *(u32x4*)(r1 + ((size_t)(lev * 8 + kt * 4 + q) * ch_rows + llocB) * 8) = svB;
        }
    }
}

// ============ Kernel 2: LSTM2 + fused heads, 2 tiles/wave ====================
// CHANGE vs r15: recurrent h single-bf16 (hfl dropped). W2ih single (r15),
// W2hh hi/lo retained. Heads hi/lo via LDS (consume hfh — unchanged).
__global__ __launch_bounds__(256, 2)
void lstm2_kern(const float* __restrict__ in_aux,
                const float* __restrict__ Wtoa1, const float* __restrict__ btoa1,
                const float* __restrict__ Wtoa2, const float* __restrict__ btoa2,
                const float* __restrict__ wsf, const u16* __restrict__ wpk,
                const u16* __restrict__ r1, int b_off, int ch_rows,
                float* __restrict__ out)
{
    __shared__ __align__(16) u16 sBhdh[32 * 70];
    __shared__ __align__(16) u16 sBhdl[32 * 70];
    __shared__ __align__(16) u16 hAh[2][16][72];
    __shared__ __align__(16) u16 hBh[2][16][72];
    const int tid = threadIdx.x;
    {
        int c = tid >> 3, p = tid & 7;   // 256 jobs exactly
        *(u32x4*)(sBhdh + c * 70 + p * 8) = *(const u32x4*)(wpk + WHD_HI + c * 64 + p * 8);
        *(u32x4*)(sBhdl + c * 70 + p * 8) = *(const u32x4*)(wpk + WHD_LO + c * 64 + p * 8);
    }

    const int lane = tid & 63, wv = tid >> 6;
    const int q = lane >> 4, l15 = lane & 15;
    const int llocA = blockIdx.x * 32 + l15;
    const int llocB = llocA + 16;
    const int aRowA = b_off + llocA;
    const int aRowB = b_off + llocB;
    const int crowA = b_off + blockIdx.x * 32 + q * 4;
    const int crowB = crowA + 16;
    const int unit = wv * 16 + l15;

    bf16x8 Bih_h[4][2], Bhh_h[4][2], Bhh_l[4][2];
    float bias[4];
#pragma unroll
    for (int g = 0; g < 4; ++g) {
        const int col = g * 64 + unit;
#pragma unroll
        for (int kt = 0; kt < 2; ++kt) {
            Bih_h[g][kt] = *(const bf16x8*)(wpk + W2IH_HI + col * 64 + kt * 32 + q * 8);
            Bhh_h[g][kt] = *(const bf16x8*)(wpk + W2HH_HI + col * 64 + kt * 32 + q * 8);
            Bhh_l[g][kt] = *(const bf16x8*)(wpk + W2HH_LO + col * 64 + kt * 32 + q * 8);
        }
        bias[g] = wsf[256 + col];
    }
    const float bhd = (wv < 2) ? wsf[512 + wv * 16 + l15] : 0.f;
    const int hcol70 = (wv * 16 + l15) * 70;

    bf16x8 hfhA[2], hfhB[2];
    float cstA[4], cstB[4];
    {
        const float toaA = in_aux[(size_t)aRowA * 3 + 1];
        const float toaB = in_aux[(size_t)aRowB * 3 + 1];
#pragma unroll
        for (int kt = 0; kt < 2; ++kt) {
            u32 dhA[4], dhB[4];
#pragma unroll
            for (int p = 0; p < 4; ++p) {
                int k0 = kt * 32 + q * 8 + p * 2;
                float w0 = Wtoa2[k0], b0 = btoa2[k0], w1 = Wtoa2[k0 + 1], b1 = btoa2[k0 + 1];
                float ha = fmaf(toaA, w0, b0), hb = fmaf(toaA, w1, b1);
                dhA[p] = ((u32)f2bf(hb) << 16) | f2bf(ha);
                ha = fmaf(toaB, w0, b0); hb = fmaf(toaB, w1, b1);
                dhB[p] = ((u32)f2bf(hb) << 16) | f2bf(ha);
            }
            __builtin_memcpy(&hfhA[kt], dhA, 16);
            __builtin_memcpy(&hfhB[kt], dhB, 16);
        }
#pragma unroll
        for (int r = 0; r < 4; ++r) {
            cstA[r] = fmaf(in_aux[(size_t)(crowA + r) * 3 + 1], Wtoa1[unit], btoa1[unit]);
            cstB[r] = fmaf(in_aux[(size_t)(crowB + r) * 3 + 1], Wtoa1[unit], btoa1[unit]);
        }
    }

    // pointer-bumped r1 prefetch (plane stride per lev = 8 planes)
    const size_t lstep = (size_t)8 * ch_rows * 8;
    const u16* rA0 = r1 + ((size_t)(q)     * ch_rows + llocA) * 8;
    const u16* rA1 = r1 + ((size_t)(4 + q) * ch_rows + llocA) * 8;
    const u16* rB0 = r1 + ((size_t)(q)     * ch_rows + llocB) * 8;
    const u16* rB1 = r1 + ((size_t)(4 + q) * ch_rows + llocB) * 8;
    bf16x8 pxA[2], pxB[2];
    pxA[0] = *(const bf16x8*)rA0; pxA[1] = *(const bf16x8*)rA1;
    pxB[0] = *(const bf16x8*)rB0; pxB[1] = *(const bf16x8*)rB1;
    __syncthreads();   // staging complete

#pragma unroll 1
    for (int lev = 0; lev < NLEVS; ++lev) {
        const int buf = lev & 1;
        f32x4 CA[4], CB[4];
#pragma unroll
        for (int g = 0; g < 4; ++g) {
            f32x4 a = {bias[g], bias[g], bias[g], bias[g]};
            f32x4 b = {bias[g], bias[g], bias[g], bias[g]};
#pragma unroll
            for (int kt = 0; kt < 2; ++kt) {
                a = MFMA(pxA[kt], Bih_h[g][kt], a);
                a = MFMA(hfhA[kt], Bhh_h[g][kt], a);
                a = MFMA(hfhA[kt], Bhh_l[g][kt], a);
                b = MFMA(pxB[kt], Bih_h[g][kt], b);
                b = MFMA(hfhB[kt], Bhh_h[g][kt], b);
                b = MFMA(hfhB[kt], Bhh_l[g][kt], b);
            }
            CA[g] = a;
            CB[g] = b;
        }
        // prefetch next-lev x (pointer bump; latency hides under act+LDS+barrier)
        if (lev < 59) {
            rA0 += lstep; rA1 += lstep; rB0 += lstep; rB1 += lstep;
            pxA[0] = *(const bf16x8*)rA0; pxA[1] = *(const bf16x8*)rA1;
            pxB[0] = *(const bf16x8*)rB0; pxB[1] = *(const bf16x8*)rB1;
        }
#pragma unroll
        for (int r = 0; r < 4; ++r) {
            float h = gate_act(CA[0][r], CA[1][r], CA[2][r], CA[3][r], cstA[r]);
            hAh[buf][q * 4 + r][unit] = f2bf(h);
            h = gate_act(CB[0][r], CB[1][r], CB[2][r], CB[3][r], cstB[r]);
            hBh[buf][q * 4 + r][unit] = f2bf(h);
        }
        __syncthreads();
#pragma unroll
        for (int kt = 0; kt < 2; ++kt) {
            hfhA[kt] = *(const bf16x8*)&hAh[buf][l15][kt * 32 + q * 8];
            hfhB[kt] = *(const bf16x8*)&hBh[buf][l15][kt * 32 + q * 8];
        }
        // fused heads (waves 0/1), both tiles; consume hfh — unchanged from r15
        if (wv < 2) {
            f32x4 a = {bhd, bhd, bhd, bhd};
            f32x4 b = {bhd, bhd, bhd, bhd};
#pragma unroll
            for (int kt = 0; kt < 2; ++kt) {
                const bf16x8 Hh = *(const bf16x8*)(sBhdh + hcol70 + (kt * 4 + q) * 8);
                const bf16x8 Hl = *(const bf16x8*)(sBhdl + hcol70 + (kt * 4 + q) * 8);
                a = MFMA(hfhA[kt], Hh, a);
                a = MFMA(hfhA[kt], Hl, a);
                b = MFMA(hfhB[kt], Hh, b);
                b = MFMA(hfhB[kt], Hl, b);
            }
#pragma unroll
            for (int r = 0; r < 4; ++r) {
                const size_t gbA = (size_t)(crowA + r);
                const size_t gbB = (size_t)(crowB + r);
                if (wv == 0) {
                    out[MEM_OFF + (gbA * NLEVS + lev) * 16 + l15] = tanh_(a[r]);
                    out[MEM_OFF + (gbB * NLEVS + lev) * 16 + l15] = tanh_(b[r]);
                } else {
                    if (l15 < 4) {
                        out[(gbA * NLEVS + lev) * 4 + l15] = a[r];
                        out[(gbB * NLEVS + lev) * 4 + l15] = b[r];
                    } else if (l15 < 7 && lev == NLEVS - 1) {
                        out[SFC_OFF + gbA * 3 + (l15 - 4)] = a[r];
                        out[SFC_OFF + gbB * 3 + (l15 - 4)] = b[r];
                    }
                }
            }
        }
    }
}

extern "C" void kernel_launch(void* const* d_in, const int* in_sizes, int n_in,
                              void* d_out, int out_size, void* d_ws, size_t ws_size,
                              hipStream_t stream) {
    const float* in_main = (const float*)d_in[0];
    const float* in_aux  = (const float*)d_in[1];
    const float* in_mem  = (const float*)d_in[2];
    const float* Wsfc1   = (const float*)d_in[3];
    const float* bsfc1   = (const float*)d_in[4];
    const float* Wsfc2   = (const float*)d_in[5];
    const float* bsfc2   = (const float*)d_in[6];
    const float* Wtoa1   = (const float*)d_in[7];
    const float* btoa1   = (const float*)d_in[8];
    const float* Wtoa2   = (const float*)d_in[9];
    const float* btoa2   = (const float*)d_in[10];
    const float* W1ih    = (const float*)d_in[11];
    const float* W1hh    = (const float*)d_in[12];
    const float* b1ih    = (const float*)d_in[13];
    const float* b1hh    = (const float*)d_in[14];
    const float* W2ih    = (const float*)d_in[15];
    const float* W2hh    = (const float*)d_in[16];
    const float* b2ih    = (const float*)d_in[17];
    const float* b2hh    = (const float*)d_in[18];
    const float* Wlat    = (const float*)d_in[19];
    const float* blat    = (const float*)d_in[20];
    const float* Wout    = (const float*)d_in[21];
    const float* bout    = (const float*)d_in[22];
    const float* Wsfco   = (const float*)d_in[23];
    const float* bsfco   = (const float*)d_in[24];
    float* out           = (float*)d_out;

    float* wsf    = (float*)d_ws;
    u16*   wpk    = (u16*)((char*)d_ws + WPK_BYTE_OFF);
    u16*   rbase  = (u16*)((char*)d_ws + WS_R1_BYTE_OFF);

    setup_pack<<<235, 256, 0, stream>>>(W1ih, W1hh, W2ih, W2hh, Wlat, Wout, Wsfco,
                                        b1ih, b1hh, b2ih, b2hh, blat, bout, bsfco,
                                        wsf, wpk);

    const size_t avail = (ws_size > WS_R1_BYTE_OFF) ? ws_size - WS_R1_BYTE_OFF : 0;
    // per row: xb = 60*24*2 = 2880 B, r1 = 60*64*2 = 7680 B
    const size_t per_row = 2880 + 7680;
    size_t rows = avail / per_row;
    rows &= ~(size_t)31;
    if (rows > BATCH) rows = BATCH;
    if (rows < 32) rows = 32;

    for (int off = 0; off < BATCH; off += (int)rows) {
        int nr = (BATCH - off < (int)rows) ? (BATCH - off) : (int)rows;
        u16* xb = rbase;
        u16* r1 = rbase + (size_t)nr * NLEVS * 24;
        const int njobs = nr * NLEVS * 3;
        xcvt_kern<<<(njobs + 255) / 256, 256, 0, stream>>>(in_main, in_mem, xb, off, njobs);
        lstm1_kern<<<nr / 32, 256, 0, stream>>>(
            xb, in_aux, Wsfc1, bsfc1, Wsfc2, bsfc2, wsf, wpk, r1, off, nr);
        lstm2_kern<<<nr / 32, 256, 0, stream>>>(
            in_aux, Wtoa1, btoa1, Wtoa2, btoa2, wsf, wpk, r1, off, nr, out);
    }
}